// Round 1
// baseline (50159.149 us; speedup 1.0000x reference)
//
#include <hip/hip_runtime.h>
#include <math.h>

#define Bsz 16
#define Lsz 400
#define Tsz 200
#define NMELS 80
#define ENC 512
#define PREsz 256
#define QHsz 1024
#define DHsz 1024
#define ATTNsz 128
#define NFILT 32
#define KW 31
#define PADW 15

typedef const float* __restrict__ cfp;
typedef float* __restrict__ fp;

__device__ __forceinline__ float4 ldf4(const float* p){ return *reinterpret_cast<const float4*>(p); }
__device__ __forceinline__ float sigm(float x){ return 1.0f/(1.0f + __expf(-x)); }
__device__ __forceinline__ float tanhfast(float x){
  x = fminf(fmaxf(x, -15.0f), 15.0f);
  float e = __expf(2.0f*x);
  return (e-1.0f)/(e+1.0f);
}

__global__ void kzero(fp p, int n){
  int i = blockIdx.x*256 + threadIdx.x;
  if (i < n) p[i] = 0.0f;
}

// dec_ins[t][b][:] : t==0 -> 0 (prenet of zeros is exactly 0), else prenet(teacher[b][t-1])
__global__ void kprenet(cfp teacher, cfp w1, cfp w2, fp dec_ins){
  int blk = blockIdx.x;            // 0..T*B-1
  int t = blk / Bsz, b = blk % Bsz;
  int tid = threadIdx.x;
  if (t == 0){
    dec_ins[(size_t)b*PREsz + tid] = 0.0f;
    return;
  }
  __shared__ __align__(16) float tch[80];
  __shared__ __align__(16) float h1[256];
  if (tid < 80) tch[tid] = teacher[((size_t)b*Tsz + (t-1))*NMELS + tid];
  __syncthreads();
  float a = 0.0f;
  const float* wr = w1 + (size_t)tid*80;
  #pragma unroll 8
  for (int k=0;k<80;k++) a += tch[k]*wr[k];
  h1[tid] = fmaxf(a, 0.0f);
  __syncthreads();
  float a2 = 0.0f;
  const float* wr2 = w2 + (size_t)tid*256;
  #pragma unroll 4
  for (int k=0;k<256;k+=4){
    float4 w4 = ldf4(wr2+k); float4 x4 = ldf4(&h1[k]);
    a2 += w4.x*x4.x + w4.y*x4.y + w4.z*x4.z + w4.w*x4.w;
  }
  dec_ins[((size_t)t*Bsz + b)*PREsz + tid] = fmaxf(a2, 0.0f);
}

// processed_memory[b][l][a] = sum_k memory[b][l][k] * wm[a][k]
__global__ void kpm(cfp memory, cfp wm, fp pm){
  int b = blockIdx.x >> 4, chunk = blockIdx.x & 15;
  int l0 = chunk*25;
  int tid = threadIdx.x;
  __shared__ __align__(16) float mrow[25*ENC];
  for (int i=tid; i<25*ENC; i+=256) mrow[i] = memory[((size_t)b*Lsz + l0)*ENC + i];
  __syncthreads();
  int a = tid & 127, half = tid >> 7;
  const float* wr = wm + (size_t)a*ENC;
  for (int ll = half; ll < 25; ll += 2){
    float acc = 0.0f;
    const float* mr = &mrow[ll*ENC];
    #pragma unroll 4
    for (int k=0;k<ENC;k+=4){
      float4 w4 = ldf4(wr+k), x4 = ldf4(mr+k);
      acc += w4.x*x4.x + w4.y*x4.y + w4.z*x4.z + w4.w*x4.w;
    }
    pm[((size_t)b*Lsz + l0 + ll)*ATTNsz + a] = acc;
  }
}

// Phase A: q-LSTM(t), d-LSTM(t-1), conv/location projection for step t
__global__ void __launch_bounds__(256) kphaseA(
    int t, int do_q, int do_d,
    cfp dec_ins, cfp ctx_prev, cfp qh_prev, cfp qc_prev,
    fp qh_new, fp qc_new,
    cfp dh_prev, cfp dc_prev, fp dh_new, fp dc_new,
    cfp aw_prev, cfp aws_prev, fp loc,
    cfp q_wih, cfp q_whh, cfp q_bih, cfp q_bhh,
    cfp d_wih, cfp d_whh, cfp d_bih, cfp d_bhh,
    cfp conv_w, cfp wloc)
{
  int bid = blockIdx.x;
  int tid = threadIdx.x;
  int lane = tid & 63, wv = tid >> 6;
  __shared__ __align__(16) float zsh[4][4][16];

  if (bid < 256){
    // ---- q gates: rows row = wv*1024 + j0 + jj, K = 768 (x=[dec_in,ctx]) + 1024 (qh)
    if (!do_q) return;
    int j0 = bid*4;
    const float* dec_t = dec_ins + (size_t)t*Bsz*PREsz;
    for (int jj=0;jj<4;jj++){
      int row = wv*QHsz + j0 + jj;
      float acc[16];
      #pragma unroll
      for (int b=0;b<16;b++) acc[b]=0.0f;
      {
        const float* wr = q_wih + (size_t)row*768;
        { // m=0: dec_in part (k4 in [0,64))
          int k4 = lane;
          float4 w4 = ldf4(wr + k4*4);
          #pragma unroll
          for (int b=0;b<16;b++){
            float4 x4 = ldf4(dec_t + b*PREsz + k4*4);
            acc[b] += w4.x*x4.x + w4.y*x4.y + w4.z*x4.z + w4.w*x4.w;
          }
        }
        #pragma unroll
        for (int m=1;m<3;m++){ // ctx part
          int k4 = lane + 64*m;
          float4 w4 = ldf4(wr + k4*4);
          int c4 = k4 - 64;
          #pragma unroll
          for (int b=0;b<16;b++){
            float4 x4 = ldf4(ctx_prev + b*ENC + c4*4);
            acc[b] += w4.x*x4.x + w4.y*x4.y + w4.z*x4.z + w4.w*x4.w;
          }
        }
      }
      {
        const float* wr = q_whh + (size_t)row*QHsz;
        #pragma unroll
        for (int m=0;m<4;m++){
          int k4 = lane + 64*m;
          float4 w4 = ldf4(wr + k4*4);
          #pragma unroll
          for (int b=0;b<16;b++){
            float4 x4 = ldf4(qh_prev + b*QHsz + k4*4);
            acc[b] += w4.x*x4.x + w4.y*x4.y + w4.z*x4.z + w4.w*x4.w;
          }
        }
      }
      #pragma unroll
      for (int off=32; off>0; off>>=1){
        #pragma unroll
        for (int b=0;b<16;b++) acc[b] += __shfl_xor(acc[b], off, 64);
      }
      if (lane == 0){
        float bias = q_bih[row] + q_bhh[row];
        #pragma unroll
        for (int b=0;b<16;b++) zsh[wv][jj][b] = acc[b] + bias;
      }
    }
    __syncthreads();
    if (tid < 64){
      int jj = tid >> 4, b = tid & 15;
      int j = j0 + jj;
      float zi = zsh[0][jj][b], zf = zsh[1][jj][b], zg = zsh[2][jj][b], zo = zsh[3][jj][b];
      float c = sigm(zf)*qc_prev[b*QHsz + j] + sigm(zi)*tanhfast(zg);
      float h = sigm(zo)*tanhfast(c);
      qc_new[b*QHsz + j] = c;
      qh_new[b*QHsz + j] = h;
    }
  } else if (bid < 512){
    // ---- d gates (for step t-1): K = 1536 (x=[ctx,qh]) + 1024 (dh)
    if (!do_d) return;
    int j0 = (bid-256)*4;
    for (int jj=0;jj<4;jj++){
      int row = wv*DHsz + j0 + jj;
      float acc[16];
      #pragma unroll
      for (int b=0;b<16;b++) acc[b]=0.0f;
      {
        const float* wr = d_wih + (size_t)row*1536;
        #pragma unroll
        for (int m=0;m<2;m++){ // ctx part (k4 in [0,128))
          int k4 = lane + 64*m;
          float4 w4 = ldf4(wr + k4*4);
          #pragma unroll
          for (int b=0;b<16;b++){
            float4 x4 = ldf4(ctx_prev + b*ENC + k4*4);
            acc[b] += w4.x*x4.x + w4.y*x4.y + w4.z*x4.z + w4.w*x4.w;
          }
        }
        #pragma unroll
        for (int m=2;m<6;m++){ // qh part
          int k4 = lane + 64*m;
          float4 w4 = ldf4(wr + k4*4);
          int c4 = k4 - 128;
          #pragma unroll
          for (int b=0;b<16;b++){
            float4 x4 = ldf4(qh_prev + b*QHsz + c4*4);
            acc[b] += w4.x*x4.x + w4.y*x4.y + w4.z*x4.z + w4.w*x4.w;
          }
        }
      }
      {
        const float* wr = d_whh + (size_t)row*DHsz;
        #pragma unroll
        for (int m=0;m<4;m++){
          int k4 = lane + 64*m;
          float4 w4 = ldf4(wr + k4*4);
          #pragma unroll
          for (int b=0;b<16;b++){
            float4 x4 = ldf4(dh_prev + b*DHsz + k4*4);
            acc[b] += w4.x*x4.x + w4.y*x4.y + w4.z*x4.z + w4.w*x4.w;
          }
        }
      }
      #pragma unroll
      for (int off=32; off>0; off>>=1){
        #pragma unroll
        for (int b=0;b<16;b++) acc[b] += __shfl_xor(acc[b], off, 64);
      }
      if (lane == 0){
        float bias = d_bih[row] + d_bhh[row];
        #pragma unroll
        for (int b=0;b<16;b++) zsh[wv][jj][b] = acc[b] + bias;
      }
    }
    __syncthreads();
    if (tid < 64){
      int jj = tid >> 4, b = tid & 15;
      int j = j0 + jj;
      float zi = zsh[0][jj][b], zf = zsh[1][jj][b], zg = zsh[2][jj][b], zo = zsh[3][jj][b];
      float c = sigm(zf)*dc_prev[b*DHsz + j] + sigm(zi)*tanhfast(zg);
      float h = sigm(zo)*tanhfast(c);
      dc_new[b*DHsz + j] = c;
      dh_new[b*DHsz + j] = h;
    }
  } else {
    // ---- conv + location projection (only needed if attention runs this step)
    if (!do_q) return;
    int cb = bid - 512;           // 0..127
    int b = cb >> 3, chunk = cb & 7;
    int l0 = chunk*50;
    __shared__ float hists[2][80];
    __shared__ float convo[NFILT][50];
    __shared__ float cwsh[NFILT*2*KW];
    for (int i=tid; i<NFILT*2*KW; i+=256) cwsh[i] = conv_w[i];
    for (int i=tid; i<160; i+=256){
      int c = i / 80, ii = i % 80;
      int pos = l0 - PADW + ii;
      float v = 0.0f;
      if (pos >= 0 && pos < Lsz) v = (c==0 ? aw_prev : aws_prev)[b*Lsz + pos];
      hists[c][ii] = v;
    }
    __syncthreads();
    for (int task=tid; task<NFILT*50; task+=256){
      int f = task & 31, ll = task >> 5;
      float a = 0.0f;
      const float* c0 = &cwsh[(f*2+0)*KW];
      const float* c1 = &cwsh[(f*2+1)*KW];
      #pragma unroll
      for (int k=0;k<KW;k++) a += hists[0][ll+k]*c0[k] + hists[1][ll+k]*c1[k];
      convo[f][ll] = a;
    }
    __syncthreads();
    for (int task=tid; task<50*ATTNsz; task+=256){
      int a = task & 127, ll = task >> 7;
      float s = 0.0f;
      const float* wl = wloc + a*NFILT;
      #pragma unroll
      for (int f=0;f<NFILT;f++) s += convo[f][ll]*wl[f];
      loc[((size_t)b*Lsz + l0 + ll)*ATTNsz + a] = s;
    }
  }
}

// Phase B: attention for step t (pq, energies, softmax, ctx, aws) + mel/stop for step t-1
__global__ void __launch_bounds__(256) kphaseB(
    int t, int do_attn, int do_mel,
    cfp qh_t, cfp loc, cfp pm, cfp memory,
    cfp wq, cfp vvec,
    cfp aws_prev, fp aw_new, fp aws_new, fp ctx_new,
    cfp dh_t1, cfp ctx_prev,
    cfp proj_w, cfp proj_b, cfp gate_w, cfp gate_b,
    fp out_mel, fp out_align, fp out_stop)
{
  int bid = blockIdx.x, tid = threadIdx.x;
  int lane = tid & 63, wv = tid >> 6;
  if (bid < 16){
    if (!do_attn) return;
    int b = bid;
    __shared__ __align__(16) float qhl[QHsz];
    __shared__ float pq[ATTNsz];
    __shared__ float vsh[ATTNsz];
    __shared__ float ew[Lsz];
    __shared__ float red[256];
    for (int i=tid; i<QHsz; i+=256) qhl[i] = qh_t[b*QHsz + i];
    if (tid < ATTNsz) vsh[tid] = vvec[tid];
    __syncthreads();
    // pq[r] = dot(qh[b], wq[r])
    for (int r = wv; r < ATTNsz; r += 4){
      const float* wr = wq + (size_t)r*QHsz;
      float acc = 0.0f;
      #pragma unroll
      for (int m=0;m<4;m++){
        int k4 = lane + 64*m;
        float4 w4 = ldf4(wr + k4*4);
        float4 x4 = ldf4(&qhl[k4*4]);
        acc += w4.x*x4.x + w4.y*x4.y + w4.z*x4.z + w4.w*x4.w;
      }
      #pragma unroll
      for (int off=32; off>0; off>>=1) acc += __shfl_xor(acc, off, 64);
      if (lane == 0) pq[r] = acc;
    }
    __syncthreads();
    // energies
    for (int l = tid; l < Lsz; l += 256){
      const float* lp = loc + ((size_t)b*Lsz + l)*ATTNsz;
      const float* pp = pm  + ((size_t)b*Lsz + l)*ATTNsz;
      float e = 0.0f;
      for (int a=0;a<ATTNsz;a+=4){
        float4 l4 = ldf4(lp+a), p4 = ldf4(pp+a);
        e += tanhfast(pq[a+0]+l4.x+p4.x)*vsh[a+0];
        e += tanhfast(pq[a+1]+l4.y+p4.y)*vsh[a+1];
        e += tanhfast(pq[a+2]+l4.z+p4.z)*vsh[a+2];
        e += tanhfast(pq[a+3]+l4.w+p4.w)*vsh[a+3];
      }
      ew[l] = e;
    }
    __syncthreads();
    // softmax over L
    float lm = -1e30f;
    for (int l=tid; l<Lsz; l+=256) lm = fmaxf(lm, ew[l]);
    red[tid] = lm; __syncthreads();
    for (int s=128; s>0; s>>=1){ if (tid<s) red[tid] = fmaxf(red[tid], red[tid+s]); __syncthreads(); }
    float mx = red[0]; __syncthreads();
    float ls = 0.0f;
    for (int l=tid; l<Lsz; l+=256){ float w = __expf(ew[l]-mx); ew[l] = w; ls += w; }
    red[tid] = ls; __syncthreads();
    for (int s=128; s>0; s>>=1){ if (tid<s) red[tid] += red[tid+s]; __syncthreads(); }
    float inv = 1.0f/red[0];
    for (int l=tid; l<Lsz; l+=256){
      float w = ew[l]*inv;
      ew[l] = w;
      aw_new[b*Lsz + l] = w;
      aws_new[b*Lsz + l] = aws_prev[b*Lsz + l] + w;
      out_align[((size_t)b*Tsz + t)*Lsz + l] = w;
    }
    __syncthreads();
    // ctx[b][e] = sum_l w[l] * memory[b][l][e]
    {
      int e = tid;
      float acc0 = 0.0f, acc1 = 0.0f;
      const float* mp = memory + (size_t)b*Lsz*ENC;
      for (int l=0; l<Lsz; l++){
        float w = ew[l];
        acc0 += w*mp[(size_t)l*ENC + e];
        acc1 += w*mp[(size_t)l*ENC + e + 256];
      }
      ctx_new[b*ENC + e] = acc0;
      ctx_new[b*ENC + e + 256] = acc1;
    }
  } else if (bid < 32){
    if (!do_mel) return;
    int b = bid - 16, tm = t - 1;
    __shared__ __align__(16) float feat[1536];
    for (int i=tid; i<1024; i+=256) feat[i] = dh_t1[b*DHsz + i];
    for (int i=tid; i<512;  i+=256) feat[1024+i] = ctx_prev[b*ENC + i];
    __syncthreads();
    for (int r = wv; r < 81; r += 4){
      const float* wr = (r < 80) ? (proj_w + (size_t)r*1536) : gate_w;
      float acc = 0.0f;
      #pragma unroll
      for (int m=0;m<6;m++){
        int k4 = lane + 64*m;
        float4 w4 = ldf4(wr + k4*4);
        float4 x4 = ldf4(&feat[k4*4]);
        acc += w4.x*x4.x + w4.y*x4.y + w4.z*x4.z + w4.w*x4.w;
      }
      #pragma unroll
      for (int off=32; off>0; off>>=1) acc += __shfl_xor(acc, off, 64);
      if (lane == 0){
        if (r < 80) out_mel[((size_t)b*Tsz + tm)*NMELS + r] = acc + proj_b[r];
        else        out_stop[b*Tsz + tm] = sigm(acc + gate_b[0]);
      }
    }
  }
}

extern "C" void kernel_launch(void* const* d_in, const int* in_sizes, int n_in,
                              void* d_out, int out_size, void* d_ws, size_t ws_size,
                              hipStream_t stream)
{
  const float* memory  = (const float*)d_in[0];
  const float* teacher = (const float*)d_in[2];
  const float* pre_w1  = (const float*)d_in[3];
  const float* pre_w2  = (const float*)d_in[4];
  const float* q_wih   = (const float*)d_in[5];
  const float* q_whh   = (const float*)d_in[6];
  const float* q_bih   = (const float*)d_in[7];
  const float* q_bhh   = (const float*)d_in[8];
  const float* d_wih   = (const float*)d_in[9];
  const float* d_whh   = (const float*)d_in[10];
  const float* d_bih   = (const float*)d_in[11];
  const float* d_bhh   = (const float*)d_in[12];
  const float* attn_wq   = (const float*)d_in[13];
  const float* attn_wm   = (const float*)d_in[14];
  const float* attn_conv = (const float*)d_in[15];
  const float* attn_wloc = (const float*)d_in[16];
  const float* attn_v    = (const float*)d_in[17];
  const float* proj_w  = (const float*)d_in[18];
  const float* proj_b  = (const float*)d_in[19];
  const float* gate_w  = (const float*)d_in[20];
  const float* gate_b  = (const float*)d_in[21];

  float* ws = (float*)d_ws;
  float* dec_ins = ws;              // T*B*PRE        = 819200
  float* pm      = dec_ins + 819200; // B*L*ATTN      = 819200
  float* loc     = pm + 819200;      // B*L*ATTN      = 819200
  float* qh      = loc + 819200;     // 2*B*QH        = 32768
  float* qc      = qh + 32768;
  float* dh      = qc + 32768;
  float* dc      = dh + 32768;
  float* ctx     = dc + 32768;       // 2*B*ENC       = 16384
  float* aw      = ctx + 16384;      // 2*B*L         = 12800
  float* aws     = aw + 12800;       // 2*B*L         = 12800

  float* out_mel   = (float*)d_out;
  float* out_align = out_mel + (size_t)Bsz*Tsz*NMELS;
  float* out_stop  = out_align + (size_t)Bsz*Tsz*Lsz;

  const int stateN = 131072 + 16384 + 25600; // qh..aws
  kzero<<<dim3((stateN+255)/256), dim3(256), 0, stream>>>(qh, stateN);
  kprenet<<<dim3(Tsz*Bsz), dim3(256), 0, stream>>>(teacher, pre_w1, pre_w2, dec_ins);
  kpm<<<dim3(256), dim3(256), 0, stream>>>(memory, attn_wm, pm);

  for (int t = 0; t <= Tsz; t++){
    int p = t & 1, q = 1 - p;
    kphaseA<<<dim3(640), dim3(256), 0, stream>>>(
      t, (t < Tsz) ? 1 : 0, (t > 0) ? 1 : 0,
      dec_ins, ctx + p*8192, qh + p*16384, qc + p*16384,
      qh + q*16384, qc + q*16384,
      dh + p*16384, dc + p*16384, dh + q*16384, dc + q*16384,
      aw + p*6400, aws + p*6400, loc,
      q_wih, q_whh, q_bih, q_bhh, d_wih, d_whh, d_bih, d_bhh,
      attn_conv, attn_wloc);
    kphaseB<<<dim3(32), dim3(256), 0, stream>>>(
      t, (t < Tsz) ? 1 : 0, (t > 0) ? 1 : 0,
      qh + q*16384, loc, pm, memory, attn_wq, attn_v,
      aws + p*6400, aw + q*6400, aws + q*6400, ctx + q*8192,
      dh + q*16384, ctx + p*8192,
      proj_w, proj_b, gate_w, gate_b,
      out_mel, out_align, out_stop);
  }
}

// Round 2
// 25338.872 us; speedup vs baseline: 1.9795x; 1.9795x over previous
//
#include <hip/hip_runtime.h>
#include <math.h>

#define Bsz 16
#define Lsz 400
#define Tsz 200
#define NMELS 80
#define ENC 512
#define PREsz 256
#define QHsz 1024
#define DHsz 1024
#define ATTNsz 128
#define NFILT 32
#define KW 31
#define PADW 15

typedef const float* __restrict__ cfp;
typedef float* __restrict__ fp;

__device__ __forceinline__ float4 ldf4(const float* p){ return *reinterpret_cast<const float4*>(p); }
__device__ __forceinline__ float sigm(float x){ return 1.0f/(1.0f + __expf(-x)); }
__device__ __forceinline__ float tanhfast(float x){
  x = fminf(fmaxf(x, -15.0f), 15.0f);
  float e = __expf(2.0f*x);
  return (e-1.0f)/(e+1.0f);
}

__global__ void kzero(fp p, int n){
  int i = blockIdx.x*256 + threadIdx.x;
  if (i < n) p[i] = 0.0f;
}

// dec_ins[t][b][:] : t==0 -> 0 (prenet of zeros is exactly 0), else prenet(teacher[b][t-1])
__global__ void kprenet(cfp teacher, cfp w1, cfp w2, fp dec_ins){
  int blk = blockIdx.x;            // 0..T*B-1
  int t = blk / Bsz, b = blk % Bsz;
  int tid = threadIdx.x;
  if (t == 0){
    dec_ins[(size_t)b*PREsz + tid] = 0.0f;
    return;
  }
  __shared__ __align__(16) float tch[80];
  __shared__ __align__(16) float h1[256];
  if (tid < 80) tch[tid] = teacher[((size_t)b*Tsz + (t-1))*NMELS + tid];
  __syncthreads();
  float a = 0.0f;
  const float* wr = w1 + (size_t)tid*80;
  #pragma unroll 8
  for (int k=0;k<80;k++) a += tch[k]*wr[k];
  h1[tid] = fmaxf(a, 0.0f);
  __syncthreads();
  float a2 = 0.0f;
  const float* wr2 = w2 + (size_t)tid*256;
  #pragma unroll 4
  for (int k=0;k<256;k+=4){
    float4 w4 = ldf4(wr2+k); float4 x4 = ldf4(&h1[k]);
    a2 += w4.x*x4.x + w4.y*x4.y + w4.z*x4.z + w4.w*x4.w;
  }
  dec_ins[((size_t)t*Bsz + b)*PREsz + tid] = fmaxf(a2, 0.0f);
}

// processed_memory[b][l][a] = sum_k memory[b][l][k] * wm[a][k]
__global__ void kpm(cfp memory, cfp wm, fp pm){
  int b = blockIdx.x >> 4, chunk = blockIdx.x & 15;
  int l0 = chunk*25;
  int tid = threadIdx.x;
  __shared__ __align__(16) float mrow[25*ENC];
  for (int i=tid; i<25*ENC; i+=256) mrow[i] = memory[((size_t)b*Lsz + l0)*ENC + i];
  __syncthreads();
  int a = tid & 127, half = tid >> 7;
  const float* wr = wm + (size_t)a*ENC;
  for (int ll = half; ll < 25; ll += 2){
    float acc = 0.0f;
    const float* mr = &mrow[ll*ENC];
    #pragma unroll 4
    for (int k=0;k<ENC;k+=4){
      float4 w4 = ldf4(wr+k), x4 = ldf4(mr+k);
      acc += w4.x*x4.x + w4.y*x4.y + w4.z*x4.z + w4.w*x4.w;
    }
    pm[((size_t)b*Lsz + l0 + ll)*ATTNsz + a] = acc;
  }
}

// LSTM gate GEMM + cell update, spill-free.
// Thread layout: b = tid&15, slot = (tid>>4)&7 (local j), gp = tid>>7 (gate pair).
// gp=0 -> gates (i,f); gp=1 -> gates (g,o). Each thread: 2 scalar accumulators.
// Activations staged in LDS in 256-float chunks (stride 260 -> 2-way conflicts = free).
// Weight rows broadcast across the 16 b-lanes.
__device__ __forceinline__ void lstm_part(
    int isq, int j0, int tid,
    float (*xsh)[260], float* zg_, float* zo_,
    cfp dec_t, cfp ctx_prev, cfp qh_prev, cfp dh_prev,
    cfp wih, cfp whh, cfp bih, cfp bhh,
    cfp c_prev, fp c_new, fp h_new)
{
  int b = tid & 15, slot = (tid >> 4) & 7, gp = tid >> 7;
  int j = j0 + slot;
  int rA = (gp*2)  *1024 + j;   // gate i or g
  int rB = (gp*2+1)*1024 + j;   // gate f or o
  int nch  = isq ? 7 : 10;
  int wihK = isq ? 768 : 1536;
  int wihCh= isq ? 3 : 6;
  float acc0 = 0.f, acc1 = 0.f;
  int bb = tid >> 4, quar = tid & 15;

  for (int ch = 0; ch < nch; ch++){
    // ---- stage x chunk [16 b][256] into LDS
    const float* src;
    if (isq){
      if (ch == 0)      src = dec_t    + bb*PREsz;
      else if (ch < 3)  src = ctx_prev + bb*ENC  + (ch-1)*256;
      else              src = qh_prev  + bb*QHsz + (ch-3)*256;
    } else {
      if (ch < 2)       src = ctx_prev + bb*ENC  + ch*256;
      else if (ch < 6)  src = qh_prev  + bb*QHsz + (ch-2)*256;
      else              src = dh_prev  + bb*DHsz + (ch-6)*256;
    }
    const float4* s4 = (const float4*)(src + quar*16);
    float4* dst = (float4*)&xsh[bb][quar*16];
    float4 t0 = s4[0], t1 = s4[1], t2 = s4[2], t3 = s4[3];
    dst[0]=t0; dst[1]=t1; dst[2]=t2; dst[3]=t3;
    __syncthreads();
    // ---- accumulate
    const float* wb_; int wstride, woff;
    if (ch < wihCh){ wb_ = wih; wstride = wihK; woff = ch*256; }
    else           { wb_ = whh; wstride = 1024; woff = (ch - wihCh)*256; }
    const float* w0 = wb_ + (size_t)rA*wstride + woff;
    const float* w1 = wb_ + (size_t)rB*wstride + woff;
    #pragma unroll 4
    for (int kk = 0; kk < 256; kk += 4){
      float4 x4 = ldf4(&xsh[b][kk]);
      float4 wa = ldf4(w0 + kk);
      float4 wv = ldf4(w1 + kk);
      acc0 += wa.x*x4.x + wa.y*x4.y + wa.z*x4.z + wa.w*x4.w;
      acc1 += wv.x*x4.x + wv.y*x4.y + wv.z*x4.z + wv.w*x4.w;
    }
    __syncthreads();
  }
  acc0 += bih[rA] + bhh[rA];
  acc1 += bih[rB] + bhh[rB];
  if (gp == 1){ zg_[tid & 127] = acc0; zo_[tid & 127] = acc1; }
  __syncthreads();
  if (gp == 0){
    float zg = zg_[tid], zo = zo_[tid];
    float c = sigm(acc1)*c_prev[b*1024 + j] + sigm(acc0)*tanhfast(zg);
    float h = sigm(zo)*tanhfast(c);
    c_new[b*1024 + j] = c;
    h_new[b*1024 + j] = h;
  }
}

// Phase A: q-LSTM(t) [blocks 0..127], d-LSTM(t-1) [128..255], conv+loc [256..383]
__global__ void __launch_bounds__(256) kphaseA(
    int t, int do_q, int do_d,
    cfp dec_ins, cfp ctx_prev, cfp qh_prev, cfp qc_prev,
    fp qh_new, fp qc_new,
    cfp dh_prev, cfp dc_prev, fp dh_new, fp dc_new,
    cfp aw_prev, cfp aws_prev, fp loc,
    cfp q_wih, cfp q_whh, cfp q_bih, cfp q_bhh,
    cfp d_wih, cfp d_whh, cfp d_bih, cfp d_bhh,
    cfp conv_w, cfp wloc)
{
  int bid = blockIdx.x;
  int tid = threadIdx.x;
  __shared__ __align__(16) float xsh[16][260];
  __shared__ float zg_[128], zo_[128];

  if (bid < 128){
    if (!do_q) return;
    const float* dec_t = dec_ins + (size_t)t*Bsz*PREsz;
    lstm_part(1, bid*8, tid, xsh, zg_, zo_,
              dec_t, ctx_prev, qh_prev, (cfp)nullptr,
              q_wih, q_whh, q_bih, q_bhh, qc_prev, qc_new, qh_new);
  } else if (bid < 256){
    if (!do_d) return;
    lstm_part(0, (bid-128)*8, tid, xsh, zg_, zo_,
              (cfp)nullptr, ctx_prev, qh_prev, dh_prev,
              d_wih, d_whh, d_bih, d_bhh, dc_prev, dc_new, dh_new);
  } else {
    // ---- conv + location projection for step t
    if (!do_q) return;
    int cb = bid - 256;           // 0..127
    int b = cb >> 3, chunk = cb & 7;
    int l0 = chunk*50;
    __shared__ float hists[2][80];
    __shared__ float convo[NFILT][50];
    __shared__ float cwsh[NFILT*2*KW];
    for (int i=tid; i<NFILT*2*KW; i+=256) cwsh[i] = conv_w[i];
    for (int i=tid; i<160; i+=256){
      int c = i / 80, ii = i % 80;
      int pos = l0 - PADW + ii;
      float v = 0.0f;
      if (pos >= 0 && pos < Lsz) v = (c==0 ? aw_prev : aws_prev)[b*Lsz + pos];
      hists[c][ii] = v;
    }
    __syncthreads();
    for (int task=tid; task<NFILT*50; task+=256){
      int f = task & 31, ll = task >> 5;
      float a = 0.0f;
      const float* c0 = &cwsh[(f*2+0)*KW];
      const float* c1 = &cwsh[(f*2+1)*KW];
      #pragma unroll
      for (int k=0;k<KW;k++) a += hists[0][ll+k]*c0[k] + hists[1][ll+k]*c1[k];
      convo[f][ll] = a;
    }
    __syncthreads();
    for (int task=tid; task<50*ATTNsz; task+=256){
      int a = task & 127, ll = task >> 7;
      float s = 0.0f;
      const float* wl = wloc + a*NFILT;
      #pragma unroll
      for (int f=0;f<NFILT;f++) s += convo[f][ll]*wl[f];
      loc[((size_t)b*Lsz + l0 + ll)*ATTNsz + a] = s;
    }
  }
}

// Phase B: attention for step t (blocks 0..15) + mel/stop for step t-1 (blocks 16..31)
__global__ void __launch_bounds__(256) kphaseB(
    int t, int do_attn, int do_mel,
    cfp qh_t, cfp loc, cfp pm, cfp memory,
    cfp wq, cfp vvec,
    cfp aws_prev, fp aw_new, fp aws_new, fp ctx_new,
    cfp dh_t1, cfp ctx_prev,
    cfp proj_w, cfp proj_b, cfp gate_w, cfp gate_b,
    fp out_mel, fp out_align, fp out_stop)
{
  int bid = blockIdx.x, tid = threadIdx.x;
  int lane = tid & 63, wv = tid >> 6;
  if (bid < 16){
    if (!do_attn) return;
    int b = bid;
    __shared__ __align__(16) float qhl[QHsz];
    __shared__ float pq[ATTNsz];
    __shared__ float vsh[ATTNsz];
    __shared__ float ew[Lsz];
    __shared__ float red[256];
    __shared__ __align__(16) float4 psum[128];
    for (int i=tid; i<QHsz; i+=256) qhl[i] = qh_t[b*QHsz + i];
    if (tid < ATTNsz) vsh[tid] = vvec[tid];
    __syncthreads();
    // pq[r] = dot(qh[b], wq[r])
    for (int r = wv; r < ATTNsz; r += 4){
      const float* wr = wq + (size_t)r*QHsz;
      float acc = 0.0f;
      #pragma unroll
      for (int m=0;m<4;m++){
        int k4 = lane + 64*m;
        float4 w4 = ldf4(wr + k4*4);
        float4 x4 = ldf4(&qhl[k4*4]);
        acc += w4.x*x4.x + w4.y*x4.y + w4.z*x4.z + w4.w*x4.w;
      }
      #pragma unroll
      for (int off=32; off>0; off>>=1) acc += __shfl_xor(acc, off, 64);
      if (lane == 0) pq[r] = acc;
    }
    __syncthreads();
    // energies
    for (int l = tid; l < Lsz; l += 256){
      const float* lp = loc + ((size_t)b*Lsz + l)*ATTNsz;
      const float* pp = pm  + ((size_t)b*Lsz + l)*ATTNsz;
      float e = 0.0f;
      for (int a=0;a<ATTNsz;a+=4){
        float4 l4 = ldf4(lp+a), p4 = ldf4(pp+a);
        e += tanhfast(pq[a+0]+l4.x+p4.x)*vsh[a+0];
        e += tanhfast(pq[a+1]+l4.y+p4.y)*vsh[a+1];
        e += tanhfast(pq[a+2]+l4.z+p4.z)*vsh[a+2];
        e += tanhfast(pq[a+3]+l4.w+p4.w)*vsh[a+3];
      }
      ew[l] = e;
    }
    __syncthreads();
    // softmax over L
    float lm = -1e30f;
    for (int l=tid; l<Lsz; l+=256) lm = fmaxf(lm, ew[l]);
    red[tid] = lm; __syncthreads();
    for (int s=128; s>0; s>>=1){ if (tid<s) red[tid] = fmaxf(red[tid], red[tid+s]); __syncthreads(); }
    float mx = red[0]; __syncthreads();
    float ls = 0.0f;
    for (int l=tid; l<Lsz; l+=256){ float w = __expf(ew[l]-mx); ew[l] = w; ls += w; }
    red[tid] = ls; __syncthreads();
    for (int s=128; s>0; s>>=1){ if (tid<s) red[tid] += red[tid+s]; __syncthreads(); }
    float inv = 1.0f/red[0];
    for (int l=tid; l<Lsz; l+=256){
      float w = ew[l]*inv;
      ew[l] = w;
      aw_new[b*Lsz + l] = w;
      aws_new[b*Lsz + l] = aws_prev[b*Lsz + l] + w;
      out_align[((size_t)b*Tsz + t)*Lsz + l] = w;
    }
    __syncthreads();
    // ctx[b][e] = sum_l w[l] * memory[b][l][e]  — 2-way l split, float4
    {
      int eslot = tid & 127, lh = tid >> 7;
      const float* mp = memory + (size_t)b*Lsz*ENC + eslot*4;
      float4 a = {0.f,0.f,0.f,0.f};
      #pragma unroll 4
      for (int l = lh; l < Lsz; l += 2){
        float w = ew[l];
        float4 m4 = ldf4(mp + (size_t)l*ENC);
        a.x += w*m4.x; a.y += w*m4.y; a.z += w*m4.z; a.w += w*m4.w;
      }
      if (lh == 1) psum[eslot] = a;
      __syncthreads();
      if (lh == 0){
        float4 p = psum[eslot];
        a.x += p.x; a.y += p.y; a.z += p.z; a.w += p.w;
        *reinterpret_cast<float4*>(&ctx_new[b*ENC + eslot*4]) = a;
      }
    }
  } else if (bid < 32){
    if (!do_mel) return;
    int b = bid - 16, tm = t - 1;
    __shared__ __align__(16) float feat[1536];
    for (int i=tid; i<1024; i+=256) feat[i] = dh_t1[b*DHsz + i];
    for (int i=tid; i<512;  i+=256) feat[1024+i] = ctx_prev[b*ENC + i];
    __syncthreads();
    for (int r = wv; r < 81; r += 4){
      const float* wr = (r < 80) ? (proj_w + (size_t)r*1536) : gate_w;
      float acc = 0.0f;
      #pragma unroll
      for (int m=0;m<6;m++){
        int k4 = lane + 64*m;
        float4 w4 = ldf4(wr + k4*4);
        float4 x4 = ldf4(&feat[k4*4]);
        acc += w4.x*x4.x + w4.y*x4.y + w4.z*x4.z + w4.w*x4.w;
      }
      #pragma unroll
      for (int off=32; off>0; off>>=1) acc += __shfl_xor(acc, off, 64);
      if (lane == 0){
        if (r < 80) out_mel[((size_t)b*Tsz + tm)*NMELS + r] = acc + proj_b[r];
        else        out_stop[b*Tsz + tm] = sigm(acc + gate_b[0]);
      }
    }
  }
}

extern "C" void kernel_launch(void* const* d_in, const int* in_sizes, int n_in,
                              void* d_out, int out_size, void* d_ws, size_t ws_size,
                              hipStream_t stream)
{
  const float* memory  = (const float*)d_in[0];
  const float* teacher = (const float*)d_in[2];
  const float* pre_w1  = (const float*)d_in[3];
  const float* pre_w2  = (const float*)d_in[4];
  const float* q_wih   = (const float*)d_in[5];
  const float* q_whh   = (const float*)d_in[6];
  const float* q_bih   = (const float*)d_in[7];
  const float* q_bhh   = (const float*)d_in[8];
  const float* d_wih   = (const float*)d_in[9];
  const float* d_whh   = (const float*)d_in[10];
  const float* d_bih   = (const float*)d_in[11];
  const float* d_bhh   = (const float*)d_in[12];
  const float* attn_wq   = (const float*)d_in[13];
  const float* attn_wm   = (const float*)d_in[14];
  const float* attn_conv = (const float*)d_in[15];
  const float* attn_wloc = (const float*)d_in[16];
  const float* attn_v    = (const float*)d_in[17];
  const float* proj_w  = (const float*)d_in[18];
  const float* proj_b  = (const float*)d_in[19];
  const float* gate_w  = (const float*)d_in[20];
  const float* gate_b  = (const float*)d_in[21];

  float* ws = (float*)d_ws;
  float* dec_ins = ws;               // T*B*PRE       = 819200
  float* pm      = dec_ins + 819200; // B*L*ATTN      = 819200
  float* loc     = pm + 819200;      // B*L*ATTN      = 819200
  float* qh      = loc + 819200;     // 2*B*QH        = 32768
  float* qc      = qh + 32768;
  float* dh      = qc + 32768;
  float* dc      = dh + 32768;
  float* ctx     = dc + 32768;       // 2*B*ENC       = 16384
  float* aw      = ctx + 16384;      // 2*B*L         = 12800
  float* aws     = aw + 12800;       // 2*B*L         = 12800

  float* out_mel   = (float*)d_out;
  float* out_align = out_mel + (size_t)Bsz*Tsz*NMELS;
  float* out_stop  = out_align + (size_t)Bsz*Tsz*Lsz;

  const int stateN = 131072 + 16384 + 25600; // qh..aws
  kzero<<<dim3((stateN+255)/256), dim3(256), 0, stream>>>(qh, stateN);
  kprenet<<<dim3(Tsz*Bsz), dim3(256), 0, stream>>>(teacher, pre_w1, pre_w2, dec_ins);
  kpm<<<dim3(256), dim3(256), 0, stream>>>(memory, attn_wm, pm);

  for (int t = 0; t <= Tsz; t++){
    int p = t & 1, q = 1 - p;
    kphaseA<<<dim3(384), dim3(256), 0, stream>>>(
      t, (t < Tsz) ? 1 : 0, (t > 0) ? 1 : 0,
      dec_ins, ctx + p*8192, qh + p*16384, qc + p*16384,
      qh + q*16384, qc + q*16384,
      dh + p*16384, dc + p*16384, dh + q*16384, dc + q*16384,
      aw + p*6400, aws + p*6400, loc,
      q_wih, q_whh, q_bih, q_bhh, d_wih, d_whh, d_bih, d_bhh,
      attn_conv, attn_wloc);
    kphaseB<<<dim3(32), dim3(256), 0, stream>>>(
      t, (t < Tsz) ? 1 : 0, (t > 0) ? 1 : 0,
      qh + q*16384, loc, pm, memory, attn_wq, attn_v,
      aws + p*6400, aw + q*6400, aws + q*6400, ctx + q*8192,
      dh + q*16384, ctx + p*8192,
      proj_w, proj_b, gate_w, gate_b,
      out_mel, out_align, out_stop);
  }
}

// Round 3
// 20785.178 us; speedup vs baseline: 2.4132x; 1.2191x over previous
//
#include <hip/hip_runtime.h>
#include <math.h>

#define Bsz 16
#define Lsz 400
#define Tsz 200
#define NMELS 80
#define ENC 512
#define PREsz 256
#define QHsz 1024
#define DHsz 1024
#define ATTNsz 128
#define NFILT 32
#define KW 31
#define PADW 15

typedef const float* __restrict__ cfp;
typedef float* __restrict__ fp;

__device__ __forceinline__ float4 ldf4(const float* p){ return *reinterpret_cast<const float4*>(p); }
__device__ __forceinline__ float sigm(float x){ return 1.0f/(1.0f + __expf(-x)); }
__device__ __forceinline__ float tanhfast(float x){
  x = fminf(fmaxf(x, -15.0f), 15.0f);
  float e = __expf(2.0f*x);
  return (e-1.0f)/(e+1.0f);
}

__global__ void kzero(fp p, int n){
  int i = blockIdx.x*256 + threadIdx.x;
  if (i < n) p[i] = 0.0f;
}

// dec_ins[t][b][:] : t==0 -> 0, else prenet(teacher[b][t-1])
__global__ void kprenet(cfp teacher, cfp w1, cfp w2, fp dec_ins){
  int blk = blockIdx.x;            // 0..T*B-1
  int t = blk / Bsz, b = blk % Bsz;
  int tid = threadIdx.x;
  if (t == 0){
    dec_ins[(size_t)b*PREsz + tid] = 0.0f;
    return;
  }
  __shared__ __align__(16) float tch[80];
  __shared__ __align__(16) float h1[256];
  if (tid < 80) tch[tid] = teacher[((size_t)b*Tsz + (t-1))*NMELS + tid];
  __syncthreads();
  float a = 0.0f;
  const float* wr = w1 + (size_t)tid*80;
  #pragma unroll 8
  for (int k=0;k<80;k++) a += tch[k]*wr[k];
  h1[tid] = fmaxf(a, 0.0f);
  __syncthreads();
  float a2 = 0.0f;
  const float* wr2 = w2 + (size_t)tid*256;
  #pragma unroll 4
  for (int k=0;k<256;k+=4){
    float4 w4 = ldf4(wr2+k); float4 x4 = ldf4(&h1[k]);
    a2 += w4.x*x4.x + w4.y*x4.y + w4.z*x4.z + w4.w*x4.w;
  }
  dec_ins[((size_t)t*Bsz + b)*PREsz + tid] = fmaxf(a2, 0.0f);
}

// pm[b][l][a] = sum_k memory[b][l][k] * wm[a][k] — 1600 blocks, 4 l's each
__global__ void __launch_bounds__(256) kpm(cfp memory, cfp wm, fp pm){
  int bid = blockIdx.x;
  int b = bid / 100, lc = bid % 100;
  int l0 = lc*4;
  int tid = threadIdx.x;
  __shared__ __align__(16) float mrow[4][512];
  __shared__ float psum[4][128];
  {
    const float4* s4 = (const float4*)(memory + ((size_t)b*Lsz + l0)*ENC);
    float4* d4 = (float4*)&mrow[0][0];
    d4[tid] = s4[tid];
    d4[tid+256] = s4[tid+256];
  }
  __syncthreads();
  int a = tid & 127, half = tid >> 7;
  const float* wr = wm + (size_t)a*ENC + half*256;
  float a0=0,a1=0,a2=0,a3=0;
  #pragma unroll 2
  for (int k=0;k<256;k+=4){
    float4 w4 = ldf4(wr + k);
    float4 x0 = ldf4(&mrow[0][half*256 + k]);
    float4 x1 = ldf4(&mrow[1][half*256 + k]);
    float4 x2 = ldf4(&mrow[2][half*256 + k]);
    float4 x3 = ldf4(&mrow[3][half*256 + k]);
    a0 += w4.x*x0.x + w4.y*x0.y + w4.z*x0.z + w4.w*x0.w;
    a1 += w4.x*x1.x + w4.y*x1.y + w4.z*x1.z + w4.w*x1.w;
    a2 += w4.x*x2.x + w4.y*x2.y + w4.z*x2.z + w4.w*x2.w;
    a3 += w4.x*x3.x + w4.y*x3.y + w4.z*x3.z + w4.w*x3.w;
  }
  if (half){ psum[0][a]=a0; psum[1][a]=a1; psum[2][a]=a2; psum[3][a]=a3; }
  __syncthreads();
  if (!half){
    a0 += psum[0][a]; a1 += psum[1][a]; a2 += psum[2][a]; a3 += psum[3][a];
    pm[((size_t)b*Lsz + l0+0)*ATTNsz + a] = a0;
    pm[((size_t)b*Lsz + l0+1)*ATTNsz + a] = a1;
    pm[((size_t)b*Lsz + l0+2)*ATTNsz + a] = a2;
    pm[((size_t)b*Lsz + l0+3)*ATTNsz + a] = a3;
  }
}

// KA: gate PARTIALS. q: blocks [0,448) = rg*7+c ; d: [448,1088) ; conv+loc: [1088,1216)
// Thread: b=tid&15, rl=tid>>4 owns 4 rows; one 256-wide K chunk.
__global__ void __launch_bounds__(256) kphaseA(
    int t, int do_q, int do_d,
    cfp dec_ins, cfp ctx_prev, cfp qh_prev, cfp dh_prev,
    cfp aw_prev, cfp aws_prev,
    fp qpart, fp dpart, fp loc,
    cfp q_wih, cfp q_whh, cfp d_wih, cfp d_whh,
    cfp conv_w, cfp wloc)
{
  int bid = blockIdx.x, tid = threadIdx.x;
  __shared__ __align__(16) float xsh[16][260];

  if (bid < 1088){
    int isq = (bid < 448);
    if (isq ? !do_q : !do_d) return;
    int idx = isq ? bid : (bid - 448);
    int nch = isq ? 7 : 10;
    int c = idx % nch, rg = idx / nch;
    // ---- stage x chunk [16 b][256]
    int bb = tid >> 4, quar = tid & 15;
    const float* src;
    if (isq){
      if (c == 0)      src = dec_ins + (size_t)t*Bsz*PREsz + bb*PREsz;
      else if (c < 3)  src = ctx_prev + bb*ENC  + (c-1)*256;
      else             src = qh_prev  + bb*QHsz + (c-3)*256;
    } else {
      if (c < 2)       src = ctx_prev + bb*ENC  + c*256;
      else if (c < 6)  src = qh_prev  + bb*QHsz + (c-2)*256;
      else             src = dh_prev  + bb*DHsz + (c-6)*256;
    }
    {
      const float4* s4 = (const float4*)(src + quar*16);
      float4* dst = (float4*)&xsh[bb][quar*16];
      float4 t0=s4[0], t1=s4[1], t2=s4[2], t3=s4[3];
      dst[0]=t0; dst[1]=t1; dst[2]=t2; dst[3]=t3;
    }
    __syncthreads();
    int b = tid & 15, rl = tid >> 4;
    int row0 = rg*64 + rl*4;
    const float* wb_; int wstride, woff;
    if (isq){
      if (c < 3){ wb_ = q_wih; wstride = 768;  woff = c*256; }
      else      { wb_ = q_whh; wstride = 1024; woff = (c-3)*256; }
    } else {
      if (c < 6){ wb_ = d_wih; wstride = 1536; woff = c*256; }
      else      { wb_ = d_whh; wstride = 1024; woff = (c-6)*256; }
    }
    const float* w0 = wb_ + (size_t)row0*wstride + woff;
    float a0=0.f, a1=0.f, a2=0.f, a3=0.f;
    #pragma unroll 4
    for (int k=0;k<256;k+=4){
      float4 x4 = ldf4(&xsh[b][k]);
      float4 wa = ldf4(w0 + k);
      float4 wb2 = ldf4(w0 + wstride + k);
      float4 wc = ldf4(w0 + 2*wstride + k);
      float4 wd = ldf4(w0 + 3*wstride + k);
      a0 += wa.x*x4.x + wa.y*x4.y + wa.z*x4.z + wa.w*x4.w;
      a1 += wb2.x*x4.x + wb2.y*x4.y + wb2.z*x4.z + wb2.w*x4.w;
      a2 += wc.x*x4.x + wc.y*x4.y + wc.z*x4.z + wc.w*x4.w;
      a3 += wd.x*x4.x + wd.y*x4.y + wd.z*x4.z + wd.w*x4.w;
    }
    float4 out = {a0,a1,a2,a3};
    fp part = isq ? qpart : dpart;
    *reinterpret_cast<float4*>(part + ((size_t)(c*16 + b))*4096 + row0) = out;
  } else {
    // ---- conv + location projection for step t
    if (!do_q) return;
    int cb = bid - 1088;           // 0..127
    int b = cb >> 3, chunk = cb & 7;
    int l0 = chunk*50;
    __shared__ float hists[2][80];
    __shared__ float convo[NFILT][50];
    __shared__ float cwsh[NFILT*2*KW];
    for (int i=tid; i<NFILT*2*KW; i+=256) cwsh[i] = conv_w[i];
    for (int i=tid; i<160; i+=256){
      int c = i / 80, ii = i % 80;
      int pos = l0 - PADW + ii;
      float v = 0.0f;
      if (pos >= 0 && pos < Lsz) v = (c==0 ? aw_prev : aws_prev)[b*Lsz + pos];
      hists[c][ii] = v;
    }
    __syncthreads();
    for (int task=tid; task<NFILT*50; task+=256){
      int f = task & 31, ll = task >> 5;
      float a = 0.0f;
      const float* c0 = &cwsh[(f*2+0)*KW];
      const float* c1 = &cwsh[(f*2+1)*KW];
      #pragma unroll
      for (int k=0;k<KW;k++) a += hists[0][ll+k]*c0[k] + hists[1][ll+k]*c1[k];
      convo[f][ll] = a;
    }
    __syncthreads();
    for (int task=tid; task<50*ATTNsz; task+=256){
      int a = task & 127, ll = task >> 7;
      float s = 0.0f;
      const float* wl = wloc + a*NFILT;
      #pragma unroll
      for (int f=0;f<NFILT;f++) s += convo[f][ll]*wl[f];
      loc[((size_t)b*Lsz + l0 + ll)*ATTNsz + a] = s;
    }
  }
}

// KB: blocks 0..15 = q-reduce + attention(t);  16..31 = d-reduce + mel/stop(t-1)
__global__ void __launch_bounds__(256) kphaseB(
    int t, int do_attn, int do_mel,
    cfp qpart, cfp dpart,
    cfp qc_prev, fp qh_new, fp qc_new,
    cfp dc_prev, fp dh_new, fp dc_new,
    cfp loc, cfp pm, cfp memory, cfp wq, cfp vvec,
    cfp aws_prev, fp aw_new, fp aws_new, fp ctx_new, cfp ctx_prev,
    cfp q_bih, cfp q_bhh, cfp d_bih, cfp d_bhh,
    cfp proj_w, cfp proj_b, cfp gate_w, cfp gate_b,
    fp out_mel, fp out_align, fp out_stop)
{
  int bid = blockIdx.x, tid = threadIdx.x;
  int lane = tid & 63, wv = tid >> 6;
  __shared__ __align__(16) float zsh[4096];
  __shared__ __align__(16) float qhl[QHsz];
  __shared__ float pq[ATTNsz];
  __shared__ float vsh[ATTNsz];
  __shared__ float ew[Lsz];
  __shared__ float red[256];
  __shared__ __align__(16) float4 psum[128];
  __shared__ __align__(16) float feat[1536];

  if (bid < 16){
    if (!do_attn) return;
    int b = bid;
    // ---- reduce q gate partials + bias
    #pragma unroll
    for (int i=0;i<4;i++){
      int r4 = (tid + i*256)*4;
      float4 bi = ldf4(q_bih + r4), bh = ldf4(q_bhh + r4);
      float4 a = {bi.x+bh.x, bi.y+bh.y, bi.z+bh.z, bi.w+bh.w};
      #pragma unroll
      for (int c=0;c<7;c++){
        float4 p = ldf4(qpart + ((size_t)(c*16 + b))*4096 + r4);
        a.x += p.x; a.y += p.y; a.z += p.z; a.w += p.w;
      }
      *reinterpret_cast<float4*>(&zsh[r4]) = a;
    }
    __syncthreads();
    // ---- cell update
    {
      int j4 = tid*4;
      float4 zi = ldf4(&zsh[j4]), zf = ldf4(&zsh[1024+j4]);
      float4 zg = ldf4(&zsh[2048+j4]), zo = ldf4(&zsh[3072+j4]);
      float4 cp = ldf4(qc_prev + b*QHsz + j4);
      float4 cn, hn;
      cn.x = sigm(zf.x)*cp.x + sigm(zi.x)*tanhfast(zg.x); hn.x = sigm(zo.x)*tanhfast(cn.x);
      cn.y = sigm(zf.y)*cp.y + sigm(zi.y)*tanhfast(zg.y); hn.y = sigm(zo.y)*tanhfast(cn.y);
      cn.z = sigm(zf.z)*cp.z + sigm(zi.z)*tanhfast(zg.z); hn.z = sigm(zo.z)*tanhfast(cn.z);
      cn.w = sigm(zf.w)*cp.w + sigm(zi.w)*tanhfast(zg.w); hn.w = sigm(zo.w)*tanhfast(cn.w);
      *reinterpret_cast<float4*>(qc_new + b*QHsz + j4) = cn;
      *reinterpret_cast<float4*>(qh_new + b*QHsz + j4) = hn;
      *reinterpret_cast<float4*>(&qhl[j4]) = hn;
    }
    if (tid < ATTNsz) vsh[tid] = vvec[tid];
    __syncthreads();
    // ---- pq[r] = dot(qh, wq[r])
    for (int r = wv; r < ATTNsz; r += 4){
      const float* wr = wq + (size_t)r*QHsz;
      float acc = 0.0f;
      #pragma unroll
      for (int m=0;m<4;m++){
        int k4 = lane + 64*m;
        float4 w4 = ldf4(wr + k4*4);
        float4 x4 = ldf4(&qhl[k4*4]);
        acc += w4.x*x4.x + w4.y*x4.y + w4.z*x4.z + w4.w*x4.w;
      }
      #pragma unroll
      for (int off=32; off>0; off>>=1) acc += __shfl_xor(acc, off, 64);
      if (lane == 0) pq[r] = acc;
    }
    __syncthreads();
    // ---- energies
    for (int l = tid; l < Lsz; l += 256){
      const float* lp = loc + ((size_t)b*Lsz + l)*ATTNsz;
      const float* pp = pm  + ((size_t)b*Lsz + l)*ATTNsz;
      float e = 0.0f;
      for (int a=0;a<ATTNsz;a+=4){
        float4 l4 = ldf4(lp+a), p4 = ldf4(pp+a);
        e += tanhfast(pq[a+0]+l4.x+p4.x)*vsh[a+0];
        e += tanhfast(pq[a+1]+l4.y+p4.y)*vsh[a+1];
        e += tanhfast(pq[a+2]+l4.z+p4.z)*vsh[a+2];
        e += tanhfast(pq[a+3]+l4.w+p4.w)*vsh[a+3];
      }
      ew[l] = e;
    }
    __syncthreads();
    // ---- softmax
    float lm = -1e30f;
    for (int l=tid; l<Lsz; l+=256) lm = fmaxf(lm, ew[l]);
    red[tid] = lm; __syncthreads();
    for (int s=128; s>0; s>>=1){ if (tid<s) red[tid] = fmaxf(red[tid], red[tid+s]); __syncthreads(); }
    float mx = red[0]; __syncthreads();
    float ls = 0.0f;
    for (int l=tid; l<Lsz; l+=256){ float w = __expf(ew[l]-mx); ew[l] = w; ls += w; }
    red[tid] = ls; __syncthreads();
    for (int s=128; s>0; s>>=1){ if (tid<s) red[tid] += red[tid+s]; __syncthreads(); }
    float inv = 1.0f/red[0];
    for (int l=tid; l<Lsz; l+=256){
      float w = ew[l]*inv;
      ew[l] = w;
      aw_new[b*Lsz + l] = w;
      aws_new[b*Lsz + l] = aws_prev[b*Lsz + l] + w;
      out_align[((size_t)b*Tsz + t)*Lsz + l] = w;
    }
    __syncthreads();
    // ---- ctx
    {
      int eslot = tid & 127, lh = tid >> 7;
      const float* mp = memory + (size_t)b*Lsz*ENC + eslot*4;
      float4 a = {0.f,0.f,0.f,0.f};
      #pragma unroll 8
      for (int l = lh; l < Lsz; l += 2){
        float w = ew[l];
        float4 m4 = ldf4(mp + (size_t)l*ENC);
        a.x += w*m4.x; a.y += w*m4.y; a.z += w*m4.z; a.w += w*m4.w;
      }
      if (lh == 1) psum[eslot] = a;
      __syncthreads();
      if (lh == 0){
        float4 p = psum[eslot];
        a.x += p.x; a.y += p.y; a.z += p.z; a.w += p.w;
        *reinterpret_cast<float4*>(&ctx_new[b*ENC + eslot*4]) = a;
      }
    }
  } else {
    if (!do_mel) return;
    int b = bid - 16, tm = t - 1;
    // ---- reduce d gate partials + bias
    #pragma unroll
    for (int i=0;i<4;i++){
      int r4 = (tid + i*256)*4;
      float4 bi = ldf4(d_bih + r4), bh = ldf4(d_bhh + r4);
      float4 a = {bi.x+bh.x, bi.y+bh.y, bi.z+bh.z, bi.w+bh.w};
      #pragma unroll
      for (int c=0;c<10;c++){
        float4 p = ldf4(dpart + ((size_t)(c*16 + b))*4096 + r4);
        a.x += p.x; a.y += p.y; a.z += p.z; a.w += p.w;
      }
      *reinterpret_cast<float4*>(&zsh[r4]) = a;
    }
    __syncthreads();
    {
      int j4 = tid*4;
      float4 zi = ldf4(&zsh[j4]), zf = ldf4(&zsh[1024+j4]);
      float4 zg = ldf4(&zsh[2048+j4]), zo = ldf4(&zsh[3072+j4]);
      float4 cp = ldf4(dc_prev + b*DHsz + j4);
      float4 cn, hn;
      cn.x = sigm(zf.x)*cp.x + sigm(zi.x)*tanhfast(zg.x); hn.x = sigm(zo.x)*tanhfast(cn.x);
      cn.y = sigm(zf.y)*cp.y + sigm(zi.y)*tanhfast(zg.y); hn.y = sigm(zo.y)*tanhfast(cn.y);
      cn.z = sigm(zf.z)*cp.z + sigm(zi.z)*tanhfast(zg.z); hn.z = sigm(zo.z)*tanhfast(cn.z);
      cn.w = sigm(zf.w)*cp.w + sigm(zi.w)*tanhfast(zg.w); hn.w = sigm(zo.w)*tanhfast(cn.w);
      *reinterpret_cast<float4*>(dc_new + b*DHsz + j4) = cn;
      *reinterpret_cast<float4*>(dh_new + b*DHsz + j4) = hn;
      *reinterpret_cast<float4*>(&feat[j4]) = hn;
    }
    for (int i=tid; i<512; i+=256) feat[1024+i] = ctx_prev[b*ENC + i];
    __syncthreads();
    // ---- mel / stop
    for (int r = wv; r < 81; r += 4){
      const float* wr = (r < 80) ? (proj_w + (size_t)r*1536) : gate_w;
      float acc = 0.0f;
      #pragma unroll
      for (int m=0;m<6;m++){
        int k4 = lane + 64*m;
        float4 w4 = ldf4(wr + k4*4);
        float4 x4 = ldf4(&feat[k4*4]);
        acc += w4.x*x4.x + w4.y*x4.y + w4.z*x4.z + w4.w*x4.w;
      }
      #pragma unroll
      for (int off=32; off>0; off>>=1) acc += __shfl_xor(acc, off, 64);
      if (lane == 0){
        if (r < 80) out_mel[((size_t)b*Tsz + tm)*NMELS + r] = acc + proj_b[r];
        else        out_stop[b*Tsz + tm] = sigm(acc + gate_b[0]);
      }
    }
  }
}

extern "C" void kernel_launch(void* const* d_in, const int* in_sizes, int n_in,
                              void* d_out, int out_size, void* d_ws, size_t ws_size,
                              hipStream_t stream)
{
  const float* memory  = (const float*)d_in[0];
  const float* teacher = (const float*)d_in[2];
  const float* pre_w1  = (const float*)d_in[3];
  const float* pre_w2  = (const float*)d_in[4];
  const float* q_wih   = (const float*)d_in[5];
  const float* q_whh   = (const float*)d_in[6];
  const float* q_bih   = (const float*)d_in[7];
  const float* q_bhh   = (const float*)d_in[8];
  const float* d_wih   = (const float*)d_in[9];
  const float* d_whh   = (const float*)d_in[10];
  const float* d_bih   = (const float*)d_in[11];
  const float* d_bhh   = (const float*)d_in[12];
  const float* attn_wq   = (const float*)d_in[13];
  const float* attn_wm   = (const float*)d_in[14];
  const float* attn_conv = (const float*)d_in[15];
  const float* attn_wloc = (const float*)d_in[16];
  const float* attn_v    = (const float*)d_in[17];
  const float* proj_w  = (const float*)d_in[18];
  const float* proj_b  = (const float*)d_in[19];
  const float* gate_w  = (const float*)d_in[20];
  const float* gate_b  = (const float*)d_in[21];

  float* ws = (float*)d_ws;
  float* dec_ins = ws;               // T*B*PRE       = 819200
  float* pm      = dec_ins + 819200; // B*L*ATTN      = 819200
  float* loc     = pm + 819200;      // B*L*ATTN      = 819200
  float* qpart   = loc + 819200;     // 7*16*4096     = 458752
  float* dpart   = qpart + 458752;   // 10*16*4096    = 655360
  float* qh      = dpart + 655360;   // 2*B*QH        = 32768
  float* qc      = qh + 32768;
  float* dh      = qc + 32768;
  float* dc      = dh + 32768;
  float* ctx     = dc + 32768;       // 2*B*ENC       = 16384
  float* aw      = ctx + 16384;      // 2*B*L         = 12800
  float* aws     = aw + 12800;       // 2*B*L         = 12800

  float* out_mel   = (float*)d_out;
  float* out_align = out_mel + (size_t)Bsz*Tsz*NMELS;
  float* out_stop  = out_align + (size_t)Bsz*Tsz*Lsz;

  const int stateN = 131072 + 16384 + 25600; // qh..aws (both ping-pong sides)
  kzero<<<dim3((stateN+255)/256), dim3(256), 0, stream>>>(qh, stateN);
  kprenet<<<dim3(Tsz*Bsz), dim3(256), 0, stream>>>(teacher, pre_w1, pre_w2, dec_ins);
  kpm<<<dim3(1600), dim3(256), 0, stream>>>(memory, attn_wm, pm);

  for (int t = 0; t <= Tsz; t++){
    int p = t & 1, q = 1 - p;
    kphaseA<<<dim3(1216), dim3(256), 0, stream>>>(
      t, (t < Tsz) ? 1 : 0, (t > 0) ? 1 : 0,
      dec_ins, ctx + p*8192, qh + p*16384, dh + p*16384,
      aw + p*6400, aws + p*6400,
      qpart, dpart, loc,
      q_wih, q_whh, d_wih, d_whh,
      attn_conv, attn_wloc);
    kphaseB<<<dim3(32), dim3(256), 0, stream>>>(
      t, (t < Tsz) ? 1 : 0, (t > 0) ? 1 : 0,
      qpart, dpart,
      qc + p*16384, qh + q*16384, qc + q*16384,
      dc + p*16384, dh + q*16384, dc + q*16384,
      loc, pm, memory, attn_wq, attn_v,
      aws + p*6400, aw + q*6400, aws + q*6400, ctx + q*8192, ctx + p*8192,
      q_bih, q_bhh, d_bih, d_bhh,
      proj_w, proj_b, gate_w, gate_b,
      out_mel, out_align, out_stop);
  }
}

// Round 4
// 17113.052 us; speedup vs baseline: 2.9310x; 1.2146x over previous
//
#include <hip/hip_runtime.h>
#include <math.h>

#define Bsz 16
#define Lsz 400
#define Tsz 200
#define NMELS 80
#define ENC 512
#define PREsz 256
#define QHsz 1024
#define DHsz 1024
#define ATTNsz 128
#define NFILT 32
#define KW 31
#define PADW 15

typedef const float* __restrict__ cfp;
typedef float* __restrict__ fp;

__device__ __forceinline__ float4 ldf4(const float* p){ return *reinterpret_cast<const float4*>(p); }
__device__ __forceinline__ float sigm(float x){ return 1.0f/(1.0f + __expf(-x)); }
__device__ __forceinline__ float tanhfast(float x){
  x = fminf(fmaxf(x, -15.0f), 15.0f);
  float e = __expf(2.0f*x);
  return (e-1.0f)/(e+1.0f);
}
// LDS skew helpers (break 128/64-float power-of-2 strides)
#define QSK(j) ((j) + ((((j)>>7))<<2))   // +4 per 128 floats
#define FSK(j) ((j) + ((((j)>>6))<<2))   // +4 per 64 floats

__global__ void kzero(fp p, int n){
  int i = blockIdx.x*256 + threadIdx.x;
  if (i < n) p[i] = 0.0f;
}

// prenet: 208 blocks (b, 16-t chunk); weights streamed once per block, reused x16
__global__ void __launch_bounds__(256) kprenet2(cfp teacher, cfp w1, cfp w2, fp dec_ins){
  int b = blockIdx.x & 15, tc = blockIdx.x >> 4;
  int t0 = tc*16;
  int tid = threadIdx.x;
  __shared__ __align__(16) float tch[16][80];
  __shared__ __align__(16) float h1[16][256];
  for (int idx = tid; idx < 16*80; idx += 256){
    int i = idx / 80, k = idx % 80;
    int t = t0 + i;
    float v = 0.f;
    if (t >= 1 && t < Tsz) v = teacher[((size_t)b*Tsz + (t-1))*NMELS + k];
    tch[i][k] = v;
  }
  __syncthreads();
  {
    int r = tid;
    float acc[16];
    #pragma unroll
    for (int i=0;i<16;i++) acc[i]=0.f;
    const float* wr = w1 + (size_t)r*80;
    for (int k=0;k<80;k++){
      float w = wr[k];
      #pragma unroll
      for (int i=0;i<16;i++) acc[i] += w * tch[i][k];
    }
    #pragma unroll
    for (int i=0;i<16;i++) h1[i][r] = fmaxf(acc[i], 0.f);
  }
  __syncthreads();
  {
    int r = tid;
    float acc[16];
    #pragma unroll
    for (int i=0;i<16;i++) acc[i]=0.f;
    const float* wr = w2 + (size_t)r*256;
    for (int k=0;k<256;k++){
      float w = wr[k];
      #pragma unroll
      for (int i=0;i<16;i++) acc[i] += w * h1[i][k];
    }
    for (int i=0;i<16;i++){
      int t = t0 + i;
      if (t < Tsz){
        float v = (t == 0) ? 0.f : fmaxf(acc[i], 0.f);
        dec_ins[((size_t)t*Bsz + b)*PREsz + r] = v;
      }
    }
  }
}

// pm: 400 blocks (b, 16-l chunk); wm row streamed once, reused x16
__global__ void __launch_bounds__(256) kpm2(cfp memory, cfp wm, fp pm){
  int b = blockIdx.x / 25, lc = blockIdx.x % 25;
  int l0 = lc*16;
  int tid = threadIdx.x;
  __shared__ __align__(16) float mrow[16][512];
  {
    const float4* s4 = (const float4*)(memory + ((size_t)b*Lsz + l0)*ENC);
    float4* d4 = (float4*)&mrow[0][0];
    #pragma unroll
    for (int i=0;i<8;i++) d4[tid + i*256] = s4[tid + i*256];
  }
  __syncthreads();
  int a = tid & 127, g = tid >> 7;
  const float* wr = wm + (size_t)a*ENC;
  float acc[8];
  #pragma unroll
  for (int i=0;i<8;i++) acc[i]=0.f;
  for (int k=0;k<512;k+=4){
    float4 w4 = ldf4(wr + k);
    #pragma unroll
    for (int i=0;i<8;i++){
      float4 x4 = ldf4(&mrow[g*8+i][k]);
      acc[i] += w4.x*x4.x + w4.y*x4.y + w4.z*x4.z + w4.w*x4.w;
    }
  }
  #pragma unroll
  for (int i=0;i<8;i++)
    pm[((size_t)b*Lsz + l0 + g*8 + i)*ATTNsz + a] = acc[i];
}

// kgates: q-partials(t) [0,448) ; d-partials(t-1) [448,1088) ; conv+loc(t) [1088,1216)
__global__ void __launch_bounds__(256) kgates(
    int t, int do_q, int do_d,
    cfp dec_ins, cfp ctx_prev, cfp qh_prev, cfp dh_prev,
    cfp aw_prev, cfp aws_prev,
    fp qpart, fp dpart, fp loc,
    cfp q_wih, cfp q_whh, cfp d_wih, cfp d_whh,
    cfp conv_w, cfp wloc)
{
  int bid = blockIdx.x, tid = threadIdx.x;
  __shared__ __align__(16) float xsh[16][260];

  if (bid < 1088){
    int isq = (bid < 448);
    if (isq ? !do_q : !do_d) return;
    int idx = isq ? bid : (bid - 448);
    int nch = isq ? 7 : 10;
    int c = idx % nch, rg = idx / nch;
    int bb = tid >> 4, quar = tid & 15;
    const float* src;
    if (isq){
      if (c == 0)      src = dec_ins + (size_t)t*Bsz*PREsz + bb*PREsz;
      else if (c < 3)  src = ctx_prev + bb*ENC  + (c-1)*256;
      else             src = qh_prev  + bb*QHsz + (c-3)*256;
    } else {
      if (c < 2)       src = ctx_prev + bb*ENC  + c*256;
      else if (c < 6)  src = qh_prev  + bb*QHsz + (c-2)*256;
      else             src = dh_prev  + bb*DHsz + (c-6)*256;
    }
    {
      const float4* s4 = (const float4*)(src + quar*16);
      float4* dst = (float4*)&xsh[bb][quar*16];
      float4 t0=s4[0], t1=s4[1], t2=s4[2], t3=s4[3];
      dst[0]=t0; dst[1]=t1; dst[2]=t2; dst[3]=t3;
    }
    __syncthreads();
    int b = tid & 15, rl = tid >> 4;
    int row0 = rg*64 + rl*4;
    const float* wb_; int wstride, woff;
    if (isq){
      if (c < 3){ wb_ = q_wih; wstride = 768;  woff = c*256; }
      else      { wb_ = q_whh; wstride = 1024; woff = (c-3)*256; }
    } else {
      if (c < 6){ wb_ = d_wih; wstride = 1536; woff = c*256; }
      else      { wb_ = d_whh; wstride = 1024; woff = (c-6)*256; }
    }
    const float* w0 = wb_ + (size_t)row0*wstride + woff;
    const float* xrow = &xsh[b][0];
    float a0=0.f, a1=0.f, a2=0.f, a3=0.f;
    for (int kb = 0; kb < 256; kb += 16){
      float4 w[4][4];
      #pragma unroll
      for (int r=0;r<4;r++){
        const float* wr = w0 + r*wstride + kb;
        w[r][0]=ldf4(wr); w[r][1]=ldf4(wr+4); w[r][2]=ldf4(wr+8); w[r][3]=ldf4(wr+12);
      }
      #pragma unroll
      for (int kk=0;kk<4;kk++){
        float4 x4 = ldf4(xrow + kb + kk*4);
        a0 += w[0][kk].x*x4.x + w[0][kk].y*x4.y + w[0][kk].z*x4.z + w[0][kk].w*x4.w;
        a1 += w[1][kk].x*x4.x + w[1][kk].y*x4.y + w[1][kk].z*x4.z + w[1][kk].w*x4.w;
        a2 += w[2][kk].x*x4.x + w[2][kk].y*x4.y + w[2][kk].z*x4.z + w[2][kk].w*x4.w;
        a3 += w[3][kk].x*x4.x + w[3][kk].y*x4.y + w[3][kk].z*x4.z + w[3][kk].w*x4.w;
      }
    }
    float4 out = {a0,a1,a2,a3};
    fp part = isq ? qpart : dpart;
    *reinterpret_cast<float4*>(part + ((size_t)(c*16 + b))*4096 + row0) = out;
  } else {
    if (!do_q) return;
    int cb = bid - 1088;
    int b = cb >> 3, chunk = cb & 7;
    int l0 = chunk*50;
    __shared__ float hists[2][80];
    __shared__ float convo[NFILT][50];
    __shared__ float cwsh[NFILT*2*KW];
    for (int i=tid; i<NFILT*2*KW; i+=256) cwsh[i] = conv_w[i];
    for (int i=tid; i<160; i+=256){
      int c = i / 80, ii = i % 80;
      int pos = l0 - PADW + ii;
      float v = 0.0f;
      if (pos >= 0 && pos < Lsz) v = (c==0 ? aw_prev : aws_prev)[b*Lsz + pos];
      hists[c][ii] = v;
    }
    __syncthreads();
    for (int task=tid; task<NFILT*50; task+=256){
      int f = task & 31, ll = task >> 5;
      float a = 0.0f;
      const float* c0 = &cwsh[(f*2+0)*KW];
      const float* c1 = &cwsh[(f*2+1)*KW];
      #pragma unroll
      for (int k=0;k<KW;k++) a += hists[0][ll+k]*c0[k] + hists[1][ll+k]*c1[k];
      convo[f][ll] = a;
    }
    __syncthreads();
    for (int task=tid; task<50*ATTNsz; task+=256){
      int a = task & 127, ll = task >> 7;
      float s = 0.0f;
      const float* wl = wloc + a*NFILT;
      #pragma unroll
      for (int f=0;f<NFILT;f++) s += convo[f][ll]*wl[f];
      loc[((size_t)b*Lsz + l0 + ll)*ATTNsz + a] = s;
    }
  }
}

// kcell: [0,64) = (b,quarter): q-reduce+cell (dup x4) + pq quarter ; [64,80) = d-reduce+cell
__global__ void __launch_bounds__(256) kcell(
    int t, int do_q, int do_d,
    cfp qpart, cfp dpart,
    cfp qc_prev, fp qh_new, fp qc_new,
    cfp dc_prev, fp dh_new, fp dc_new,
    cfp wq, fp pqws,
    cfp q_bih, cfp q_bhh, cfp d_bih, cfp d_bhh)
{
  int bid = blockIdx.x, tid = threadIdx.x;
  __shared__ __align__(16) float zsh[4096];
  __shared__ __align__(16) float qhl[1056];
  if (bid < 64){
    if (!do_q) return;
    int b = bid & 15, quarter = bid >> 4;
    #pragma unroll
    for (int i=0;i<4;i++){
      int r4 = (tid + i*256)*4;
      float4 bi = ldf4(q_bih + r4), bh = ldf4(q_bhh + r4);
      float4 a = {bi.x+bh.x, bi.y+bh.y, bi.z+bh.z, bi.w+bh.w};
      #pragma unroll
      for (int c=0;c<7;c++){
        float4 p = ldf4(qpart + ((size_t)(c*16 + b))*4096 + r4);
        a.x += p.x; a.y += p.y; a.z += p.z; a.w += p.w;
      }
      *reinterpret_cast<float4*>(&zsh[r4]) = a;
    }
    __syncthreads();
    {
      int j4 = tid*4;
      float4 zi = ldf4(&zsh[j4]), zf = ldf4(&zsh[1024+j4]);
      float4 zg = ldf4(&zsh[2048+j4]), zo = ldf4(&zsh[3072+j4]);
      float4 cp = ldf4(qc_prev + b*QHsz + j4);
      float4 cn, hn;
      cn.x = sigm(zf.x)*cp.x + sigm(zi.x)*tanhfast(zg.x); hn.x = sigm(zo.x)*tanhfast(cn.x);
      cn.y = sigm(zf.y)*cp.y + sigm(zi.y)*tanhfast(zg.y); hn.y = sigm(zo.y)*tanhfast(cn.y);
      cn.z = sigm(zf.z)*cp.z + sigm(zi.z)*tanhfast(zg.z); hn.z = sigm(zo.z)*tanhfast(cn.z);
      cn.w = sigm(zf.w)*cp.w + sigm(zi.w)*tanhfast(zg.w); hn.w = sigm(zo.w)*tanhfast(cn.w);
      if (quarter == 0){
        *reinterpret_cast<float4*>(qc_new + b*QHsz + j4) = cn;
        *reinterpret_cast<float4*>(qh_new + b*QHsz + j4) = hn;
      }
      *reinterpret_cast<float4*>(&qhl[QSK(j4)]) = hn;
    }
    __syncthreads();
    {
      int r = quarter*32 + (tid>>3);
      int koff = (tid&7)*128;
      const float* wr = wq + (size_t)r*QHsz + koff;
      const float* xr = &qhl[QSK(koff)];
      float acc = 0.f;
      #pragma unroll 8
      for (int k=0;k<128;k+=4){
        float4 w4 = ldf4(wr+k), x4 = ldf4(xr+k);
        acc += w4.x*x4.x + w4.y*x4.y + w4.z*x4.z + w4.w*x4.w;
      }
      acc += __shfl_xor(acc, 1, 64);
      acc += __shfl_xor(acc, 2, 64);
      acc += __shfl_xor(acc, 4, 64);
      if ((tid&7) == 0) pqws[b*ATTNsz + r] = acc;
    }
  } else {
    if (!do_d) return;
    int b = bid - 64;
    #pragma unroll
    for (int i=0;i<4;i++){
      int r4 = (tid + i*256)*4;
      float4 bi = ldf4(d_bih + r4), bh = ldf4(d_bhh + r4);
      float4 a = {bi.x+bh.x, bi.y+bh.y, bi.z+bh.z, bi.w+bh.w};
      #pragma unroll
      for (int c=0;c<10;c++){
        float4 p = ldf4(dpart + ((size_t)(c*16 + b))*4096 + r4);
        a.x += p.x; a.y += p.y; a.z += p.z; a.w += p.w;
      }
      *reinterpret_cast<float4*>(&zsh[r4]) = a;
    }
    __syncthreads();
    {
      int j4 = tid*4;
      float4 zi = ldf4(&zsh[j4]), zf = ldf4(&zsh[1024+j4]);
      float4 zg = ldf4(&zsh[2048+j4]), zo = ldf4(&zsh[3072+j4]);
      float4 cp = ldf4(dc_prev + b*DHsz + j4);
      float4 cn, hn;
      cn.x = sigm(zf.x)*cp.x + sigm(zi.x)*tanhfast(zg.x); hn.x = sigm(zo.x)*tanhfast(cn.x);
      cn.y = sigm(zf.y)*cp.y + sigm(zi.y)*tanhfast(zg.y); hn.y = sigm(zo.y)*tanhfast(cn.y);
      cn.z = sigm(zf.z)*cp.z + sigm(zi.z)*tanhfast(zg.z); hn.z = sigm(zo.z)*tanhfast(cn.z);
      cn.w = sigm(zf.w)*cp.w + sigm(zi.w)*tanhfast(zg.w); hn.w = sigm(zo.w)*tanhfast(cn.w);
      *reinterpret_cast<float4*>(dc_new + b*DHsz + j4) = cn;
      *reinterpret_cast<float4*>(dh_new + b*DHsz + j4) = hn;
    }
  }
}

// kattn: [0,64) = (b,lc): energies chunk + local softmax stats ; [64,96) = (b,half): mel/stop(t-1)
__global__ void __launch_bounds__(256) kattn(
    int t, int do_attn, int do_mel,
    cfp pqws, cfp loc, cfp pm, cfp vvec,
    fp ebuf, fp emax, fp esum,
    cfp dh_t1, cfp ctx_prev,
    cfp proj_w, cfp proj_b, cfp gate_w, cfp gate_b,
    fp out_mel, fp out_stop)
{
  int bid = blockIdx.x, tid = threadIdx.x;
  if (bid < 64){
    if (!do_attn) return;
    int b = bid & 15, lc = bid >> 4;
    int l0 = lc*100;
    __shared__ float pqv[128], vsh[128];
    __shared__ float esh[100];
    __shared__ float red[256];
    if (tid < 128) pqv[tid] = pqws[b*ATTNsz + tid];
    else if (tid < 256) vsh[tid-128] = vvec[tid-128];
    __syncthreads();
    int ll = tid >> 1, ah = tid & 1;
    float e = 0.f;
    if (ll < 100){
      int l = l0 + ll;
      const float* lp = loc + ((size_t)b*Lsz + l)*ATTNsz + ah*64;
      const float* pp = pm  + ((size_t)b*Lsz + l)*ATTNsz + ah*64;
      const float* pqa = &pqv[ah*64];
      const float* va  = &vsh[ah*64];
      #pragma unroll 4
      for (int a=0;a<64;a+=4){
        float4 l4 = ldf4(lp+a), p4 = ldf4(pp+a);
        e += tanhfast(pqa[a+0]+l4.x+p4.x)*va[a+0];
        e += tanhfast(pqa[a+1]+l4.y+p4.y)*va[a+1];
        e += tanhfast(pqa[a+2]+l4.z+p4.z)*va[a+2];
        e += tanhfast(pqa[a+3]+l4.w+p4.w)*va[a+3];
      }
    }
    e += __shfl_xor(e, 1, 64);
    if (ll < 100 && ah == 0) esh[ll] = e;
    __syncthreads();
    float lm = -1e30f;
    for (int i=tid; i<100; i+=256) lm = fmaxf(lm, esh[i]);
    red[tid] = lm; __syncthreads();
    for (int s=128; s>0; s>>=1){ if (tid<s) red[tid] = fmaxf(red[tid], red[tid+s]); __syncthreads(); }
    float mx = red[0]; __syncthreads();
    float ls = 0.f;
    for (int i=tid; i<100; i+=256) ls += __expf(esh[i]-mx);
    red[tid] = ls; __syncthreads();
    for (int s=128; s>0; s>>=1){ if (tid<s) red[tid] += red[tid+s]; __syncthreads(); }
    for (int i=tid; i<100; i+=256) ebuf[b*Lsz + l0 + i] = esh[i];
    if (tid == 0){ emax[b*4+lc] = mx; esum[b*4+lc] = red[0]; }
  } else {
    if (!do_mel) return;
    int mb = bid - 64;
    int b = mb & 15, half = mb >> 4;
    int tm = t - 1;
    int lane = tid & 63, wv = tid >> 6;
    __shared__ __align__(16) float feat[1632];
    for (int i=tid; i<1024; i+=256) feat[FSK(i)] = dh_t1[b*DHsz + i];
    for (int i=tid; i<512;  i+=256) feat[FSK(1024+i)] = ctx_prev[b*ENC + i];
    __syncthreads();
    int rbeg = half*40, rend = half ? 81 : 40;
    for (int r = rbeg + wv; r < rend; r += 4){
      const float* wr = (r < 80) ? (proj_w + (size_t)r*1536) : gate_w;
      float acc = 0.0f;
      #pragma unroll
      for (int m=0;m<6;m++){
        int k = (lane + 64*m)*4;
        float4 w4 = ldf4(wr + k);
        float4 x4 = ldf4(&feat[FSK(k)]);
        acc += w4.x*x4.x + w4.y*x4.y + w4.z*x4.z + w4.w*x4.w;
      }
      #pragma unroll
      for (int off=32; off>0; off>>=1) acc += __shfl_xor(acc, off, 64);
      if (lane == 0){
        if (r < 80) out_mel[((size_t)b*Tsz + tm)*NMELS + r] = acc + proj_b[r];
        else        out_stop[b*Tsz + tm] = sigm(acc + gate_b[0]);
      }
    }
  }
}

// kctx: 64 blocks (b, ec): softmax finalize + ctx slice + (ec==0) aw/aws/align
__global__ void __launch_bounds__(256) kctx(
    int t, cfp ebuf, cfp emax, cfp esum, cfp memory,
    cfp aws_prev, fp aw_new, fp aws_new, fp ctx_new, fp out_align)
{
  int b = blockIdx.x & 15, ec = blockIdx.x >> 4;
  int tid = threadIdx.x;
  __shared__ float wsh[Lsz];
  __shared__ float gstat[2];
  __shared__ __align__(16) float4 psum[8][32];
  if (tid == 0){
    float m0=emax[b*4+0], m1=emax[b*4+1], m2=emax[b*4+2], m3=emax[b*4+3];
    float gm = fmaxf(fmaxf(m0,m1), fmaxf(m2,m3));
    float gs = esum[b*4+0]*__expf(m0-gm) + esum[b*4+1]*__expf(m1-gm)
             + esum[b*4+2]*__expf(m2-gm) + esum[b*4+3]*__expf(m3-gm);
    gstat[0] = gm; gstat[1] = 1.0f/gs;
  }
  __syncthreads();
  float gm = gstat[0], ginv = gstat[1];
  for (int l=tid; l<Lsz; l+=256) wsh[l] = __expf(ebuf[b*Lsz+l]-gm)*ginv;
  __syncthreads();
  if (ec == 0){
    for (int l=tid; l<Lsz; l+=256){
      float w = wsh[l];
      aw_new[b*Lsz+l] = w;
      aws_new[b*Lsz+l] = aws_prev[b*Lsz+l] + w;
      out_align[((size_t)b*Tsz + t)*Lsz + l] = w;
    }
  }
  int e4 = tid & 31, lh = tid >> 5;
  const float* mp = memory + (size_t)b*Lsz*ENC + ec*128 + e4*4;
  float4 a = {0.f,0.f,0.f,0.f};
  for (int l = lh; l < Lsz; l += 8){
    float w = wsh[l];
    float4 m4 = ldf4(mp + (size_t)l*ENC);
    a.x += w*m4.x; a.y += w*m4.y; a.z += w*m4.z; a.w += w*m4.w;
  }
  if (lh > 0) psum[lh][e4] = a;
  __syncthreads();
  if (lh == 0){
    #pragma unroll
    for (int i=1;i<8;i++){
      float4 p = psum[i][e4];
      a.x += p.x; a.y += p.y; a.z += p.z; a.w += p.w;
    }
    *reinterpret_cast<float4*>(&ctx_new[b*ENC + ec*128 + e4*4]) = a;
  }
}

extern "C" void kernel_launch(void* const* d_in, const int* in_sizes, int n_in,
                              void* d_out, int out_size, void* d_ws, size_t ws_size,
                              hipStream_t stream)
{
  const float* memory  = (const float*)d_in[0];
  const float* teacher = (const float*)d_in[2];
  const float* pre_w1  = (const float*)d_in[3];
  const float* pre_w2  = (const float*)d_in[4];
  const float* q_wih   = (const float*)d_in[5];
  const float* q_whh   = (const float*)d_in[6];
  const float* q_bih   = (const float*)d_in[7];
  const float* q_bhh   = (const float*)d_in[8];
  const float* d_wih   = (const float*)d_in[9];
  const float* d_whh   = (const float*)d_in[10];
  const float* d_bih   = (const float*)d_in[11];
  const float* d_bhh   = (const float*)d_in[12];
  const float* attn_wq   = (const float*)d_in[13];
  const float* attn_wm   = (const float*)d_in[14];
  const float* attn_conv = (const float*)d_in[15];
  const float* attn_wloc = (const float*)d_in[16];
  const float* attn_v    = (const float*)d_in[17];
  const float* proj_w  = (const float*)d_in[18];
  const float* proj_b  = (const float*)d_in[19];
  const float* gate_w  = (const float*)d_in[20];
  const float* gate_b  = (const float*)d_in[21];

  float* ws = (float*)d_ws;
  float* dec_ins = ws;               // 819200
  float* pm      = dec_ins + 819200; // 819200
  float* loc     = pm + 819200;      // 819200
  float* qpart   = loc + 819200;     // 458752
  float* dpart   = qpart + 458752;   // 655360
  float* pqws    = dpart + 655360;   // 2048
  float* ebuf    = pqws + 2048;      // 6400
  float* emax    = ebuf + 6400;      // 64
  float* esum    = emax + 64;        // 64
  float* qh      = esum + 64;        // 32768 (x2 ping-pong)
  float* qc      = qh + 32768;
  float* dh      = qc + 32768;
  float* dc      = dh + 32768;
  float* ctx     = dc + 32768;       // 16384
  float* aw      = ctx + 16384;      // 12800
  float* aws     = aw + 12800;       // 12800

  float* out_mel   = (float*)d_out;
  float* out_align = out_mel + (size_t)Bsz*Tsz*NMELS;
  float* out_stop  = out_align + (size_t)Bsz*Tsz*Lsz;

  const int stateN = 131072 + 16384 + 25600;
  kzero<<<dim3((stateN+255)/256), dim3(256), 0, stream>>>(qh, stateN);
  kprenet2<<<dim3(16*13), dim3(256), 0, stream>>>(teacher, pre_w1, pre_w2, dec_ins);
  kpm2<<<dim3(400), dim3(256), 0, stream>>>(memory, attn_wm, pm);

  for (int t = 0; t <= Tsz; t++){
    int p = t & 1, q = 1 - p;
    int do_q = (t < Tsz) ? 1 : 0;
    int do_d = (t > 0) ? 1 : 0;
    kgates<<<dim3(1216), dim3(256), 0, stream>>>(
      t, do_q, do_d,
      dec_ins, ctx + p*8192, qh + p*16384, dh + p*16384,
      aw + p*6400, aws + p*6400,
      qpart, dpart, loc,
      q_wih, q_whh, d_wih, d_whh,
      attn_conv, attn_wloc);
    kcell<<<dim3(80), dim3(256), 0, stream>>>(
      t, do_q, do_d,
      qpart, dpart,
      qc + p*16384, qh + q*16384, qc + q*16384,
      dc + p*16384, dh + q*16384, dc + q*16384,
      attn_wq, pqws,
      q_bih, q_bhh, d_bih, d_bhh);
    kattn<<<dim3(96), dim3(256), 0, stream>>>(
      t, do_q, do_d,
      pqws, loc, pm, attn_v,
      ebuf, emax, esum,
      dh + q*16384, ctx + p*8192,
      proj_w, proj_b, gate_w, gate_b,
      out_mel, out_stop);
    if (t < Tsz){
      kctx<<<dim3(64), dim3(256), 0, stream>>>(
        t, ebuf, emax, esum, memory,
        aws + p*6400, aw + q*6400, aws + q*6400, ctx + q*8192, out_align);
    }
  }
}

// Round 5
// 15076.781 us; speedup vs baseline: 3.3269x; 1.1351x over previous
//
#include <hip/hip_runtime.h>
#include <math.h>

#define Bsz 16
#define Lsz 400
#define Tsz 200
#define NMELS 80
#define ENC 512
#define PREsz 256
#define QHsz 1024
#define DHsz 1024
#define ATTNsz 128
#define NFILT 32
#define KW 31
#define PADW 15

typedef const float* __restrict__ cfp;
typedef float* __restrict__ fp;

__device__ __forceinline__ float4 ldf4(const float* p){ return *reinterpret_cast<const float4*>(p); }
__device__ __forceinline__ float sigm(float x){ return 1.0f/(1.0f + __expf(-x)); }
__device__ __forceinline__ float tanhfast(float x){
  x = fminf(fmaxf(x, -15.0f), 15.0f);
  float e = __expf(2.0f*x);
  return (e-1.0f)/(e+1.0f);
}
#define QSK(j) ((j) + ((((j)>>7))<<2))   // +4 per 128 floats
#define FSK(j) ((j) + ((((j)>>6))<<2))   // +4 per 64 floats

__global__ void kzero(fp p, int n){
  int i = blockIdx.x*256 + threadIdx.x;
  if (i < n) p[i] = 0.0f;
}

// prenet (one-time): 208 blocks (b, 16-t chunk)
__global__ void __launch_bounds__(256) kprenet2(cfp teacher, cfp w1, cfp w2, fp dec_ins){
  int b = blockIdx.x & 15, tc = blockIdx.x >> 4;
  int t0 = tc*16;
  int tid = threadIdx.x;
  __shared__ __align__(16) float tch[16][80];
  __shared__ __align__(16) float h1[16][256];
  for (int idx = tid; idx < 16*80; idx += 256){
    int i = idx / 80, k = idx % 80;
    int t = t0 + i;
    float v = 0.f;
    if (t >= 1 && t < Tsz) v = teacher[((size_t)b*Tsz + (t-1))*NMELS + k];
    tch[i][k] = v;
  }
  __syncthreads();
  {
    int r = tid;
    float acc[16];
    #pragma unroll
    for (int i=0;i<16;i++) acc[i]=0.f;
    const float* wr = w1 + (size_t)r*80;
    for (int k=0;k<80;k++){
      float w = wr[k];
      #pragma unroll
      for (int i=0;i<16;i++) acc[i] += w * tch[i][k];
    }
    #pragma unroll
    for (int i=0;i<16;i++) h1[i][r] = fmaxf(acc[i], 0.f);
  }
  __syncthreads();
  {
    int r = tid;
    float acc[16];
    #pragma unroll
    for (int i=0;i<16;i++) acc[i]=0.f;
    const float* wr = w2 + (size_t)r*256;
    for (int k=0;k<256;k++){
      float w = wr[k];
      #pragma unroll
      for (int i=0;i<16;i++) acc[i] += w * h1[i][k];
    }
    for (int i=0;i<16;i++){
      int t = t0 + i;
      if (t < Tsz){
        float v = (t == 0) ? 0.f : fmaxf(acc[i], 0.f);
        dec_ins[((size_t)t*Bsz + b)*PREsz + r] = v;
      }
    }
  }
}

// pm (one-time): 400 blocks
__global__ void __launch_bounds__(256) kpm2(cfp memory, cfp wm, fp pm){
  int b = blockIdx.x / 25, lc = blockIdx.x % 25;
  int l0 = lc*16;
  int tid = threadIdx.x;
  __shared__ __align__(16) float mrow[16][512];
  {
    const float4* s4 = (const float4*)(memory + ((size_t)b*Lsz + l0)*ENC);
    float4* d4 = (float4*)&mrow[0][0];
    #pragma unroll
    for (int i=0;i<8;i++) d4[tid + i*256] = s4[tid + i*256];
  }
  __syncthreads();
  int a = tid & 127, g = tid >> 7;
  const float* wr = wm + (size_t)a*ENC;
  float acc[8];
  #pragma unroll
  for (int i=0;i<8;i++) acc[i]=0.f;
  for (int k=0;k<512;k+=4){
    float4 w4 = ldf4(wr + k);
    #pragma unroll
    for (int i=0;i<8;i++){
      float4 x4 = ldf4(&mrow[g*8+i][k]);
      acc[i] += w4.x*x4.x + w4.y*x4.y + w4.z*x4.z + w4.w*x4.w;
    }
  }
  #pragma unroll
  for (int i=0;i<8;i++)
    pm[((size_t)b*Lsz + l0 + g*8 + i)*ATTNsz + a] = acc[i];
}

// ---------------- P1: gates + conv + aws-updater ----------------
// blocks: [0,448) q-gates(t) ; [448,1088) d-gates(t-1) ; [1088,1216) conv(t) ; [1216,1232) updater(t-1)
__global__ void __launch_bounds__(256) kgatesA(
    int t, int do_q, int do_d,
    cfp dec_ins, cfp qh_state, cfp dh_state,
    cfp cpartP, cfp emaxP, cfp esumP, cfp ebufP,
    cfp awsP, fp awsQ,
    fp qpart, fp dpart, fp loc, fp out_align,
    cfp q_wih, cfp q_whh, cfp d_wih, cfp d_whh,
    cfp conv_w, cfp wloc)
{
  int bid = blockIdx.x, tid = threadIdx.x;
  __shared__ __align__(16) float xsh[16][260];

  if (bid < 1088){
    int isq = (bid < 448);
    if (isq ? !do_q : !do_d) return;
    int idx = isq ? bid : (bid - 448);
    int nch = isq ? 7 : 10;
    int c = idx % nch, rg = idx / nch;
    int bb = tid >> 4, quar = tid & 15;
    // source classification
    int is_ctx = isq ? (c >= 1 && c <= 2) : (c <= 1);
    int ctxoff = isq ? (c-1)*256 : c*256;
    float4* dst = (float4*)&xsh[bb][quar*16];
    if (is_ctx){
      if (!do_d){ // t==0: ctx(-1)=0
        float4 z4 = {0.f,0.f,0.f,0.f};
        dst[0]=z4; dst[1]=z4; dst[2]=z4; dst[3]=z4;
      } else {
        float m0=emaxP[bb*4+0], m1=emaxP[bb*4+1], m2=emaxP[bb*4+2], m3=emaxP[bb*4+3];
        float gm = fmaxf(fmaxf(m0,m1), fmaxf(m2,m3));
        float e0=__expf(m0-gm), e1=__expf(m1-gm), e2=__expf(m2-gm), e3=__expf(m3-gm);
        float gs = esumP[bb*4+0]*e0 + esumP[bb*4+1]*e1 + esumP[bb*4+2]*e2 + esumP[bb*4+3]*e3;
        float inv = 1.0f/gs;
        float s0=e0*inv, s1=e1*inv, s2=e2*inv, s3=e3*inv;
        const float* cp = cpartP + (size_t)bb*2048 + ctxoff + quar*16;
        #pragma unroll
        for (int kk=0;kk<16;kk+=4){
          float4 p0 = ldf4(cp+kk), p1 = ldf4(cp+512+kk), p2 = ldf4(cp+1024+kk), p3 = ldf4(cp+1536+kk);
          float4 a;
          a.x = s0*p0.x + s1*p1.x + s2*p2.x + s3*p3.x;
          a.y = s0*p0.y + s1*p1.y + s2*p2.y + s3*p3.y;
          a.z = s0*p0.z + s1*p1.z + s2*p2.z + s3*p3.z;
          a.w = s0*p0.w + s1*p1.w + s2*p2.w + s3*p3.w;
          dst[kk>>2] = a;
        }
      }
    } else {
      const float* src;
      if (isq){
        if (c == 0)      src = dec_ins + (size_t)t*Bsz*PREsz + bb*PREsz;
        else             src = qh_state + bb*QHsz + (c-3)*256;
      } else {
        if (c < 6)       src = qh_state + bb*QHsz + (c-2)*256;
        else             src = dh_state + bb*DHsz + (c-6)*256;
      }
      const float4* s4 = (const float4*)(src + quar*16);
      float4 t0=s4[0], t1=s4[1], t2=s4[2], t3=s4[3];
      dst[0]=t0; dst[1]=t1; dst[2]=t2; dst[3]=t3;
    }
    __syncthreads();
    int b = tid & 15, rl = tid >> 4;
    int row0 = rg*64 + rl*4;
    const float* wb_; int wstride, woff;
    if (isq){
      if (c < 3){ wb_ = q_wih; wstride = 768;  woff = c*256; }
      else      { wb_ = q_whh; wstride = 1024; woff = (c-3)*256; }
    } else {
      if (c < 6){ wb_ = d_wih; wstride = 1536; woff = c*256; }
      else      { wb_ = d_whh; wstride = 1024; woff = (c-6)*256; }
    }
    const float* w0 = wb_ + (size_t)row0*wstride + woff;
    const float* xrow = &xsh[b][0];
    float a0=0.f, a1=0.f, a2=0.f, a3=0.f;
    for (int kb = 0; kb < 256; kb += 16){
      float4 w[4][4];
      #pragma unroll
      for (int r=0;r<4;r++){
        const float* wr = w0 + r*wstride + kb;
        w[r][0]=ldf4(wr); w[r][1]=ldf4(wr+4); w[r][2]=ldf4(wr+8); w[r][3]=ldf4(wr+12);
      }
      #pragma unroll
      for (int kk=0;kk<4;kk++){
        float4 x4 = ldf4(xrow + kb + kk*4);
        a0 += w[0][kk].x*x4.x + w[0][kk].y*x4.y + w[0][kk].z*x4.z + w[0][kk].w*x4.w;
        a1 += w[1][kk].x*x4.x + w[1][kk].y*x4.y + w[1][kk].z*x4.z + w[1][kk].w*x4.w;
        a2 += w[2][kk].x*x4.x + w[2][kk].y*x4.y + w[2][kk].z*x4.z + w[2][kk].w*x4.w;
        a3 += w[3][kk].x*x4.x + w[3][kk].y*x4.y + w[3][kk].z*x4.z + w[3][kk].w*x4.w;
      }
    }
    float4 out = {a0,a1,a2,a3};
    fp part = isq ? qpart : dpart;
    *reinterpret_cast<float4*>(part + ((size_t)(c*16 + b))*4096 + row0) = out;
  } else if (bid < 1216){
    // ---- conv + loc projection for step t (aw/aws reconstructed inline)
    if (!do_q) return;
    int cb = bid - 1088;
    int b = cb >> 3, chunk = cb & 7;
    int l0 = chunk*50;
    __shared__ float hists[2][80];
    __shared__ float convo[NFILT][50];
    __shared__ float cwsh[NFILT*2*KW];
    __shared__ float stat2[2];
    for (int i=tid; i<NFILT*2*KW; i+=256) cwsh[i] = conv_w[i];
    if (tid == 0 && do_d){
      float m0=emaxP[b*4+0], m1=emaxP[b*4+1], m2=emaxP[b*4+2], m3=emaxP[b*4+3];
      float gm = fmaxf(fmaxf(m0,m1), fmaxf(m2,m3));
      float gs = esumP[b*4+0]*__expf(m0-gm) + esumP[b*4+1]*__expf(m1-gm)
               + esumP[b*4+2]*__expf(m2-gm) + esumP[b*4+3]*__expf(m3-gm);
      stat2[0] = gm; stat2[1] = 1.0f/gs;
    }
    __syncthreads();
    float gm = stat2[0], ginv = stat2[1];
    for (int i=tid; i<80; i+=256){
      int pos = l0 - PADW + i;
      float w = 0.f, as = 0.f;
      if (do_d && pos >= 0 && pos < Lsz){
        w = __expf(ebufP[b*Lsz + pos] - gm) * ginv;
        as = awsP[b*Lsz + pos] + w;
      }
      hists[0][i] = w;
      hists[1][i] = as;
    }
    __syncthreads();
    for (int task=tid; task<NFILT*50; task+=256){
      int f = task & 31, ll = task >> 5;
      float a = 0.0f;
      const float* c0 = &cwsh[(f*2+0)*KW];
      const float* c1 = &cwsh[(f*2+1)*KW];
      #pragma unroll
      for (int k=0;k<KW;k++) a += hists[0][ll+k]*c0[k] + hists[1][ll+k]*c1[k];
      convo[f][ll] = a;
    }
    __syncthreads();
    for (int task=tid; task<50*ATTNsz; task+=256){
      int a = task & 127, ll = task >> 7;
      float s = 0.0f;
      const float* wl = wloc + a*NFILT;
      #pragma unroll
      for (int f=0;f<NFILT;f++) s += convo[f][ll]*wl[f];
      loc[((size_t)b*Lsz + l0 + ll)*ATTNsz + a] = s;
    }
  } else {
    // ---- updater: finalize aw(t-1) -> out_align, aws ping-pong
    if (!do_d) return;
    int b = bid - 1216;
    __shared__ float stat2[2];
    if (tid == 0){
      float m0=emaxP[b*4+0], m1=emaxP[b*4+1], m2=emaxP[b*4+2], m3=emaxP[b*4+3];
      float gm = fmaxf(fmaxf(m0,m1), fmaxf(m2,m3));
      float gs = esumP[b*4+0]*__expf(m0-gm) + esumP[b*4+1]*__expf(m1-gm)
               + esumP[b*4+2]*__expf(m2-gm) + esumP[b*4+3]*__expf(m3-gm);
      stat2[0] = gm; stat2[1] = 1.0f/gs;
    }
    __syncthreads();
    float gm = stat2[0], ginv = stat2[1];
    for (int l=tid; l<Lsz; l+=256){
      float w = __expf(ebufP[b*Lsz + l] - gm) * ginv;
      awsQ[b*Lsz + l] = awsP[b*Lsz + l] + w;
      out_align[((size_t)b*Tsz + (t-1))*Lsz + l] = w;
    }
  }
}

// ---------------- P2: q-cell+pq+energies+cpart ; d-cell+mel ----------------
// blocks: [0,64) = (b, lc): q path ; [64,96) = (b, half): d path
__global__ void __launch_bounds__(256) kmidB(
    int t, int do_q, int do_d,
    cfp qpart, cfp dpart,
    cfp qcP, fp qcQ, fp qh_state,
    cfp dcP, fp dcQ, fp dh_state,
    cfp wq, cfp vvec, cfp loc, cfp pm, cfp memory,
    cfp cpartP, cfp emaxP, cfp esumP,
    fp cpartQ, fp emaxQ, fp esumQ, fp ebufQ,
    cfp q_bih, cfp q_bhh, cfp d_bih, cfp d_bhh,
    cfp proj_w, cfp proj_b, cfp gate_w, cfp gate_b,
    fp out_mel, fp out_stop)
{
  int bid = blockIdx.x, tid = threadIdx.x;
  __shared__ __align__(16) float zsh[4096];
  if (bid < 64){
    if (!do_q) return;
    int b = bid & 15, lc = bid >> 4;
    int l0 = lc*100;
    __shared__ __align__(16) float qhl[1056];
    __shared__ float pqv[128], vsh[128];
    __shared__ float esh[100], pesh[100];
    __shared__ float red[256];
    __shared__ __align__(16) float4 psum[128];
    // 1. reduce q partials + bias
    #pragma unroll
    for (int i=0;i<4;i++){
      int r4 = (tid + i*256)*4;
      float4 bi = ldf4(q_bih + r4), bh = ldf4(q_bhh + r4);
      float4 a = {bi.x+bh.x, bi.y+bh.y, bi.z+bh.z, bi.w+bh.w};
      #pragma unroll
      for (int c=0;c<7;c++){
        float4 p = ldf4(qpart + ((size_t)(c*16 + b))*4096 + r4);
        a.x += p.x; a.y += p.y; a.z += p.z; a.w += p.w;
      }
      *reinterpret_cast<float4*>(&zsh[r4]) = a;
    }
    __syncthreads();
    // 2. cell
    {
      int j4 = tid*4;
      float4 zi = ldf4(&zsh[j4]), zf = ldf4(&zsh[1024+j4]);
      float4 zg = ldf4(&zsh[2048+j4]), zo = ldf4(&zsh[3072+j4]);
      float4 cp = ldf4(qcP + b*QHsz + j4);
      float4 cn, hn;
      cn.x = sigm(zf.x)*cp.x + sigm(zi.x)*tanhfast(zg.x); hn.x = sigm(zo.x)*tanhfast(cn.x);
      cn.y = sigm(zf.y)*cp.y + sigm(zi.y)*tanhfast(zg.y); hn.y = sigm(zo.y)*tanhfast(cn.y);
      cn.z = sigm(zf.z)*cp.z + sigm(zi.z)*tanhfast(zg.z); hn.z = sigm(zo.z)*tanhfast(cn.z);
      cn.w = sigm(zf.w)*cp.w + sigm(zi.w)*tanhfast(zg.w); hn.w = sigm(zo.w)*tanhfast(cn.w);
      if (lc == 0){
        *reinterpret_cast<float4*>(qcQ + b*QHsz + j4) = cn;
        *reinterpret_cast<float4*>(qh_state + b*QHsz + j4) = hn;
      }
      *reinterpret_cast<float4*>(&qhl[QSK(j4)]) = hn;
    }
    if (tid < 128) vsh[tid] = vvec[tid];
    __syncthreads();
    // 3. pq = wq . qh  (2 threads per row)
    {
      int r = tid >> 1, kh = tid & 1;
      int koff = kh*512;
      const float* wr = wq + (size_t)r*QHsz + koff;
      float acc = 0.f;
      #pragma unroll 8
      for (int k=0;k<512;k+=4){
        float4 w4 = ldf4(wr+k), x4 = ldf4(&qhl[QSK(koff + k)]);
        acc += w4.x*x4.x + w4.y*x4.y + w4.z*x4.z + w4.w*x4.w;
      }
      acc += __shfl_xor(acc, 1, 64);
      if (kh == 0) pqv[r] = acc;
    }
    __syncthreads();
    // 4. energies for 100 l's
    {
      int ll = tid >> 1, ah = tid & 1;
      float e = 0.f;
      if (ll < 100){
        int l = l0 + ll;
        const float* lp = loc + ((size_t)b*Lsz + l)*ATTNsz + ah*64;
        const float* pp = pm  + ((size_t)b*Lsz + l)*ATTNsz + ah*64;
        const float* pqa = &pqv[ah*64];
        const float* va  = &vsh[ah*64];
        #pragma unroll 4
        for (int a=0;a<64;a+=4){
          float4 l4 = ldf4(lp+a), p4 = ldf4(pp+a);
          e += tanhfast(pqa[a+0]+l4.x+p4.x)*va[a+0];
          e += tanhfast(pqa[a+1]+l4.y+p4.y)*va[a+1];
          e += tanhfast(pqa[a+2]+l4.z+p4.z)*va[a+2];
          e += tanhfast(pqa[a+3]+l4.w+p4.w)*va[a+3];
        }
      }
      e += __shfl_xor(e, 1, 64);
      if (ll < 100 && ah == 0) esh[ll] = e;
    }
    __syncthreads();
    // 5. local softmax stats
    float lm = -1e30f;
    for (int i=tid; i<100; i+=256) lm = fmaxf(lm, esh[i]);
    red[tid] = lm; __syncthreads();
    for (int s=128; s>0; s>>=1){ if (tid<s) red[tid] = fmaxf(red[tid], red[tid+s]); __syncthreads(); }
    float mx = red[0]; __syncthreads();
    float ls = 0.f;
    for (int i=tid; i<100; i+=256){ float p = __expf(esh[i]-mx); pesh[i] = p; ls += p; }
    red[tid] = ls; __syncthreads();
    for (int s=128; s>0; s>>=1){ if (tid<s) red[tid] += red[tid+s]; __syncthreads(); }
    for (int i=tid; i<100; i+=256) ebufQ[b*Lsz + l0 + i] = esh[i];
    if (tid == 0){ emaxQ[b*4+lc] = mx; esumQ[b*4+lc] = red[0]; }
    __syncthreads();
    // 6. cpart[e] = sum_l pesh[l] * mem[l][e]
    {
      int e4 = tid & 127, lh = tid >> 7;
      const float* mp = memory + ((size_t)b*Lsz + l0)*ENC + e4*4;
      float4 a = {0.f,0.f,0.f,0.f};
      for (int l = lh*50; l < lh*50+50; l++){
        float w = pesh[l];
        float4 m4 = ldf4(mp + (size_t)l*ENC);
        a.x += w*m4.x; a.y += w*m4.y; a.z += w*m4.z; a.w += w*m4.w;
      }
      if (lh == 1) psum[e4] = a;
      __syncthreads();
      if (lh == 0){
        float4 p = psum[e4];
        a.x += p.x; a.y += p.y; a.z += p.z; a.w += p.w;
        *reinterpret_cast<float4*>(cpartQ + ((size_t)b*4 + lc)*512 + e4*4) = a;
      }
    }
  } else {
    if (!do_d) return;
    int db = bid - 64;
    int b = db & 15, half = db >> 4;
    int tm = t - 1;
    int lane = tid & 63, wv = tid >> 6;
    __shared__ __align__(16) float feat[1632];
    __shared__ float scs[4];
    // 1. reduce d partials + bias
    #pragma unroll
    for (int i=0;i<4;i++){
      int r4 = (tid + i*256)*4;
      float4 bi = ldf4(d_bih + r4), bh = ldf4(d_bhh + r4);
      float4 a = {bi.x+bh.x, bi.y+bh.y, bi.z+bh.z, bi.w+bh.w};
      #pragma unroll
      for (int c=0;c<10;c++){
        float4 p = ldf4(dpart + ((size_t)(c*16 + b))*4096 + r4);
        a.x += p.x; a.y += p.y; a.z += p.z; a.w += p.w;
      }
      *reinterpret_cast<float4*>(&zsh[r4]) = a;
    }
    if (tid == 0){
      float m0=emaxP[b*4+0], m1=emaxP[b*4+1], m2=emaxP[b*4+2], m3=emaxP[b*4+3];
      float gm = fmaxf(fmaxf(m0,m1), fmaxf(m2,m3));
      float e0=__expf(m0-gm), e1=__expf(m1-gm), e2=__expf(m2-gm), e3=__expf(m3-gm);
      float gs = esumP[b*4+0]*e0 + esumP[b*4+1]*e1 + esumP[b*4+2]*e2 + esumP[b*4+3]*e3;
      float inv = 1.0f/gs;
      scs[0]=e0*inv; scs[1]=e1*inv; scs[2]=e2*inv; scs[3]=e3*inv;
    }
    __syncthreads();
    // 2. cell
    {
      int j4 = tid*4;
      float4 zi = ldf4(&zsh[j4]), zf = ldf4(&zsh[1024+j4]);
      float4 zg = ldf4(&zsh[2048+j4]), zo = ldf4(&zsh[3072+j4]);
      float4 cp = ldf4(dcP + b*DHsz + j4);
      float4 cn, hn;
      cn.x = sigm(zf.x)*cp.x + sigm(zi.x)*tanhfast(zg.x); hn.x = sigm(zo.x)*tanhfast(cn.x);
      cn.y = sigm(zf.y)*cp.y + sigm(zi.y)*tanhfast(zg.y); hn.y = sigm(zo.y)*tanhfast(cn.y);
      cn.z = sigm(zf.z)*cp.z + sigm(zi.z)*tanhfast(zg.z); hn.z = sigm(zo.z)*tanhfast(cn.z);
      cn.w = sigm(zf.w)*cp.w + sigm(zi.w)*tanhfast(zg.w); hn.w = sigm(zo.w)*tanhfast(cn.w);
      if (half == 0){
        *reinterpret_cast<float4*>(dcQ + b*DHsz + j4) = cn;
        *reinterpret_cast<float4*>(dh_state + b*DHsz + j4) = hn;
      }
      feat[FSK(j4+0)] = hn.x; feat[FSK(j4+1)] = hn.y;
      feat[FSK(j4+2)] = hn.z; feat[FSK(j4+3)] = hn.w;
    }
    __syncthreads();
    // 3. ctx(t-1) finalize into feat[1024..1536)
    {
      float s0=scs[0], s1=scs[1], s2=scs[2], s3=scs[3];
      for (int i=tid; i<512; i+=256){
        const float* cp = cpartP + (size_t)b*2048 + i;
        float v = s0*cp[0] + s1*cp[512] + s2*cp[1024] + s3*cp[1536];
        feat[FSK(1024+i)] = v;
      }
    }
    __syncthreads();
    // 4. mel / stop
    int rbeg = half*40, rend = half ? 81 : 40;
    for (int r = rbeg + wv; r < rend; r += 4){
      const float* wr = (r < 80) ? (proj_w + (size_t)r*1536) : gate_w;
      float acc = 0.0f;
      #pragma unroll
      for (int m=0;m<6;m++){
        int k = (lane + 64*m)*4;
        float4 w4 = ldf4(wr + k);
        float4 x4;
        x4.x = feat[FSK(k+0)]; x4.y = feat[FSK(k+1)];
        x4.z = feat[FSK(k+2)]; x4.w = feat[FSK(k+3)];
        acc += w4.x*x4.x + w4.y*x4.y + w4.z*x4.z + w4.w*x4.w;
      }
      #pragma unroll
      for (int off=32; off>0; off>>=1) acc += __shfl_xor(acc, off, 64);
      if (lane == 0){
        if (r < 80) out_mel[((size_t)b*Tsz + tm)*NMELS + r] = acc + proj_b[r];
        else        out_stop[b*Tsz + tm] = sigm(acc + gate_b[0]);
      }
    }
  }
}

extern "C" void kernel_launch(void* const* d_in, const int* in_sizes, int n_in,
                              void* d_out, int out_size, void* d_ws, size_t ws_size,
                              hipStream_t stream)
{
  const float* memory  = (const float*)d_in[0];
  const float* teacher = (const float*)d_in[2];
  const float* pre_w1  = (const float*)d_in[3];
  const float* pre_w2  = (const float*)d_in[4];
  const float* q_wih   = (const float*)d_in[5];
  const float* q_whh   = (const float*)d_in[6];
  const float* q_bih   = (const float*)d_in[7];
  const float* q_bhh   = (const float*)d_in[8];
  const float* d_wih   = (const float*)d_in[9];
  const float* d_whh   = (const float*)d_in[10];
  const float* d_bih   = (const float*)d_in[11];
  const float* d_bhh   = (const float*)d_in[12];
  const float* attn_wq   = (const float*)d_in[13];
  const float* attn_wm   = (const float*)d_in[14];
  const float* attn_conv = (const float*)d_in[15];
  const float* attn_wloc = (const float*)d_in[16];
  const float* attn_v    = (const float*)d_in[17];
  const float* proj_w  = (const float*)d_in[18];
  const float* proj_b  = (const float*)d_in[19];
  const float* gate_w  = (const float*)d_in[20];
  const float* gate_b  = (const float*)d_in[21];

  float* ws = (float*)d_ws;
  float* dec_ins  = ws;                 // 819200
  float* pm       = dec_ins + 819200;   // 819200
  float* loc      = pm + 819200;        // 819200
  float* qpart    = loc + 819200;       // 458752
  float* dpart    = qpart + 458752;     // 655360
  float* ebuf2    = dpart + 655360;     // 2*6400
  float* emax2    = ebuf2 + 12800;      // 2*64
  float* esum2    = emax2 + 128;        // 2*64
  float* cpart2   = esum2 + 128;        // 2*32768
  float* qh_state = cpart2 + 65536;     // 16384
  float* dh_state = qh_state + 16384;   // 16384
  float* qc2      = dh_state + 16384;   // 2*16384
  float* dc2      = qc2 + 32768;        // 2*16384
  float* aws2     = dc2 + 32768;        // 2*6400

  float* out_mel   = (float*)d_out;
  float* out_align = out_mel + (size_t)Bsz*Tsz*NMELS;
  float* out_stop  = out_align + (size_t)Bsz*Tsz*Lsz;

  const int stateN = 16384+16384+32768+32768+12800; // qh_state..aws2
  kzero<<<dim3((stateN+255)/256), dim3(256), 0, stream>>>(qh_state, stateN);
  kprenet2<<<dim3(16*13), dim3(256), 0, stream>>>(teacher, pre_w1, pre_w2, dec_ins);
  kpm2<<<dim3(400), dim3(256), 0, stream>>>(memory, attn_wm, pm);

  for (int t = 0; t <= Tsz; t++){
    int pp = (t+1)&1, qq = t&1;
    int do_q = (t < Tsz) ? 1 : 0;
    int do_d = (t > 0) ? 1 : 0;
    kgatesA<<<dim3(1232), dim3(256), 0, stream>>>(
      t, do_q, do_d,
      dec_ins, qh_state, dh_state,
      cpart2 + pp*32768, emax2 + pp*64, esum2 + pp*64, ebuf2 + pp*6400,
      aws2 + pp*6400, aws2 + qq*6400,
      qpart, dpart, loc, out_align,
      q_wih, q_whh, d_wih, d_whh,
      attn_conv, attn_wloc);
    kmidB<<<dim3(96), dim3(256), 0, stream>>>(
      t, do_q, do_d,
      qpart, dpart,
      qc2 + pp*16384, qc2 + qq*16384, qh_state,
      dc2 + pp*16384, dc2 + qq*16384, dh_state,
      attn_wq, attn_v, loc, pm, memory,
      cpart2 + pp*32768, emax2 + pp*64, esum2 + pp*64,
      cpart2 + qq*32768, emax2 + qq*64, esum2 + qq*64, ebuf2 + qq*6400,
      q_bih, q_bhh, d_bih, d_bhh,
      proj_w, proj_b, gate_w, gate_b,
      out_mel, out_stop);
  }
}

// Round 7
// 12128.946 us; speedup vs baseline: 4.1355x; 1.2430x over previous
//
#include <hip/hip_runtime.h>
#include <math.h>

#define Bsz 16
#define Lsz 400
#define Tsz 200
#define NMELS 80
#define ENC 512
#define PREsz 256
#define QHsz 1024
#define DHsz 1024
#define ATTNsz 128
#define NFILT 32
#define KW 31
#define PADW 15

typedef const float* __restrict__ cfp;
typedef float* __restrict__ fp;
typedef __fp16 hf;
typedef __fp16 h2 __attribute__((ext_vector_type(2)));
typedef const hf* __restrict__ chp;

union F4H { float4 f; h2 h[4]; };

__device__ __forceinline__ float4 ldf4(const float* p){ return *reinterpret_cast<const float4*>(p); }
__device__ __forceinline__ float sigm(float x){ return 1.0f/(1.0f + __expf(-x)); }
__device__ __forceinline__ float tanhfast(float x){
  x = fminf(fmaxf(x, -15.0f), 15.0f);
  float e = __expf(2.0f*x);
  return (e-1.0f)/(e+1.0f);
}
__device__ __forceinline__ h2 pk2(float a, float b){
  return __builtin_amdgcn_cvt_pkrtz(a, b);
}
__device__ __forceinline__ float fdot2f(h2 a, h2 b, float c){
#if __has_builtin(__builtin_amdgcn_fdot2)
  return __builtin_amdgcn_fdot2(a, b, c, false);
#else
  return c + (float)a.x*(float)b.x + (float)a.y*(float)b.y;
#endif
}

__global__ void kzero(fp p, int n){
  int i = blockIdx.x*256 + threadIdx.x;
  if (i < n) p[i] = 0.0f;
}

// fp32 -> fp16 conversion (one-time per launch)
__global__ void kcvt(cfp src, hf* __restrict__ dst, int n){
  int i = (blockIdx.x*256 + threadIdx.x)*4;
  if (i + 3 < n){
    float4 v = ldf4(src + i);
    dst[i+0] = (hf)v.x; dst[i+1] = (hf)v.y; dst[i+2] = (hf)v.z; dst[i+3] = (hf)v.w;
  } else {
    for (int k=i; k<n; k++) dst[k] = (hf)src[k];
  }
}

// prenet (one-time): 208 blocks (b, 16-t chunk)
__global__ void __launch_bounds__(256) kprenet2(cfp teacher, cfp w1, cfp w2, fp dec_ins){
  int b = blockIdx.x & 15, tc = blockIdx.x >> 4;
  int t0 = tc*16;
  int tid = threadIdx.x;
  __shared__ __align__(16) float tch[16][80];
  __shared__ __align__(16) float h1[16][256];
  for (int idx = tid; idx < 16*80; idx += 256){
    int i = idx / 80, k = idx % 80;
    int t = t0 + i;
    float v = 0.f;
    if (t >= 1 && t < Tsz) v = teacher[((size_t)b*Tsz + (t-1))*NMELS + k];
    tch[i][k] = v;
  }
  __syncthreads();
  {
    int r = tid;
    float acc[16];
    #pragma unroll
    for (int i=0;i<16;i++) acc[i]=0.f;
    const float* wr = w1 + (size_t)r*80;
    for (int k=0;k<80;k++){
      float w = wr[k];
      #pragma unroll
      for (int i=0;i<16;i++) acc[i] += w * tch[i][k];
    }
    #pragma unroll
    for (int i=0;i<16;i++) h1[i][r] = fmaxf(acc[i], 0.f);
  }
  __syncthreads();
  {
    int r = tid;
    float acc[16];
    #pragma unroll
    for (int i=0;i<16;i++) acc[i]=0.f;
    const float* wr = w2 + (size_t)r*256;
    for (int k=0;k<256;k++){
      float w = wr[k];
      #pragma unroll
      for (int i=0;i<16;i++) acc[i] += w * h1[i][k];
    }
    for (int i=0;i<16;i++){
      int t = t0 + i;
      if (t < Tsz){
        float v = (t == 0) ? 0.f : fmaxf(acc[i], 0.f);
        dec_ins[((size_t)t*Bsz + b)*PREsz + r] = v;
      }
    }
  }
}

// pm (one-time): 400 blocks
__global__ void __launch_bounds__(256) kpm2(cfp memory, cfp wm, fp pm){
  int b = blockIdx.x / 25, lc = blockIdx.x % 25;
  int l0 = lc*16;
  int tid = threadIdx.x;
  __shared__ __align__(16) float mrow[16][512];
  {
    const float4* s4 = (const float4*)(memory + ((size_t)b*Lsz + l0)*ENC);
    float4* d4 = (float4*)&mrow[0][0];
    #pragma unroll
    for (int i=0;i<8;i++) d4[tid + i*256] = s4[tid + i*256];
  }
  __syncthreads();
  int a = tid & 127, g = tid >> 7;
  const float* wr = wm + (size_t)a*ENC;
  float acc[8];
  #pragma unroll
  for (int i=0;i<8;i++) acc[i]=0.f;
  for (int k=0;k<512;k+=4){
    float4 w4 = ldf4(wr + k);
    #pragma unroll
    for (int i=0;i<8;i++){
      float4 x4 = ldf4(&mrow[g*8+i][k]);
      acc[i] += w4.x*x4.x + w4.y*x4.y + w4.z*x4.z + w4.w*x4.w;
    }
  }
  #pragma unroll
  for (int i=0;i<8;i++)
    pm[((size_t)b*Lsz + l0 + g*8 + i)*ATTNsz + a] = acc[i];
}

struct GateSmem { __align__(16) h2 xsh[16][132]; };   // 16 x 256 halves, skewed stride
struct ConvSmem { float hists[2][80]; float convo[NFILT][50]; float cwsh[NFILT*2*KW]; float stat2[2]; };
union SMemA { GateSmem g; ConvSmem c; };

// ---------------- P1: gates(fp16 weights) + conv + aws-updater ----------------
// blocks: [0,896) q-gates(t) ; [896,2176) d-gates(t-1) ; [2176,2304) conv(t) ; [2304,2320) updater(t-1)
__global__ void __launch_bounds__(256) kgatesA(
    int t, int do_q, int do_d,
    cfp dec_ins, cfp qh_state, cfp dh_state,
    cfp cpartP, cfp emaxP, cfp esumP, cfp ebufP,
    cfp awsP, fp awsQ,
    fp qpart, fp dpart, fp loc, fp out_align,
    chp h_qwih, chp h_qwhh, chp h_dwih, chp h_dwhh,
    cfp conv_w, cfp wloc)
{
  int bid = blockIdx.x, tid = threadIdx.x;
  __shared__ SMemA sm;

  if (bid < 2176){
    int isq = (bid < 896);
    if (isq ? !do_q : !do_d) return;
    int idx = isq ? bid : (bid - 896);
    int nch = isq ? 7 : 10;
    int c = idx % nch, rg = idx / nch;
    int bb = tid >> 4, quar = tid & 15;
    int is_ctx = isq ? (c >= 1 && c <= 2) : (c <= 1);
    int ctxoff = isq ? (c-1)*256 : c*256;
    h2* dst = &sm.g.xsh[bb][quar*8];
    if (is_ctx){
      if (!do_d){
        h2 z = pk2(0.f, 0.f);
        #pragma unroll
        for (int i=0;i<8;i++) dst[i] = z;
      } else {
        float m0=emaxP[bb*4+0], m1=emaxP[bb*4+1], m2=emaxP[bb*4+2], m3=emaxP[bb*4+3];
        float gm = fmaxf(fmaxf(m0,m1), fmaxf(m2,m3));
        float e0=__expf(m0-gm), e1=__expf(m1-gm), e2=__expf(m2-gm), e3=__expf(m3-gm);
        float gs = esumP[bb*4+0]*e0 + esumP[bb*4+1]*e1 + esumP[bb*4+2]*e2 + esumP[bb*4+3]*e3;
        float inv = 1.0f/gs;
        float s0=e0*inv, s1=e1*inv, s2=e2*inv, s3=e3*inv;
        const float* cp = cpartP + (size_t)bb*2048 + ctxoff + quar*16;
        #pragma unroll
        for (int kk=0;kk<16;kk+=4){
          float4 p0 = ldf4(cp+kk), p1 = ldf4(cp+512+kk), p2 = ldf4(cp+1024+kk), p3 = ldf4(cp+1536+kk);
          float ax = s0*p0.x + s1*p1.x + s2*p2.x + s3*p3.x;
          float ay = s0*p0.y + s1*p1.y + s2*p2.y + s3*p3.y;
          float az = s0*p0.z + s1*p1.z + s2*p2.z + s3*p3.z;
          float aw = s0*p0.w + s1*p1.w + s2*p2.w + s3*p3.w;
          dst[(kk>>1)+0] = pk2(ax, ay);
          dst[(kk>>1)+1] = pk2(az, aw);
        }
      }
    } else {
      const float* src;
      if (isq){
        if (c == 0)      src = dec_ins + (size_t)t*Bsz*PREsz + bb*PREsz;
        else             src = qh_state + bb*QHsz + (c-3)*256;
      } else {
        if (c < 6)       src = qh_state + bb*QHsz + (c-2)*256;
        else             src = dh_state + bb*DHsz + (c-6)*256;
      }
      const float4* s4 = (const float4*)(src + quar*16);
      float4 t0=s4[0], t1=s4[1], t2=s4[2], t3=s4[3];
      dst[0]=pk2(t0.x,t0.y); dst[1]=pk2(t0.z,t0.w);
      dst[2]=pk2(t1.x,t1.y); dst[3]=pk2(t1.z,t1.w);
      dst[4]=pk2(t2.x,t2.y); dst[5]=pk2(t2.z,t2.w);
      dst[6]=pk2(t3.x,t3.y); dst[7]=pk2(t3.z,t3.w);
    }
    __syncthreads();
    int b = tid & 15, rl = tid >> 4;
    int row0 = rg*32 + rl*2;
    const hf* wbase; int wstride, woff;
    if (isq){
      if (c < 3){ wbase = h_qwih; wstride = 768;  woff = c*256; }
      else      { wbase = h_qwhh; wstride = 1024; woff = (c-3)*256; }
    } else {
      if (c < 6){ wbase = h_dwih; wstride = 1536; woff = c*256; }
      else      { wbase = h_dwhh; wstride = 1024; woff = (c-6)*256; }
    }
    const h2* w0 = (const h2*)(wbase + (size_t)row0*wstride + woff);
    const h2* w1 = (const h2*)(wbase + (size_t)(row0+1)*wstride + woff);
    const h2* xr = &sm.g.xsh[b][0];
    float a0=0.f, a1=0.f;
    #pragma unroll 4
    for (int kb=0; kb<128; kb+=8){
      F4H u0, u1, u2, u3, xA, xB;
      u0.f = ldf4((const float*)(w0 + kb));
      u1.f = ldf4((const float*)(w0 + kb + 4));
      u2.f = ldf4((const float*)(w1 + kb));
      u3.f = ldf4((const float*)(w1 + kb + 4));
      xA.f = ldf4((const float*)(xr + kb));
      xB.f = ldf4((const float*)(xr + kb + 4));
      #pragma unroll
      for (int j=0;j<4;j++){
        a0 = fdot2f(u0.h[j], xA.h[j], a0);
        a0 = fdot2f(u1.h[j], xB.h[j], a0);
        a1 = fdot2f(u2.h[j], xA.h[j], a1);
        a1 = fdot2f(u3.h[j], xB.h[j], a1);
      }
    }
    float2 out = {a0, a1};
    fp part = isq ? qpart : dpart;
    *reinterpret_cast<float2*>(part + ((size_t)(c*16 + b))*4096 + row0) = out;
  } else if (bid < 2304){
    // ---- conv + loc projection for step t (aw/aws reconstructed inline)
    if (!do_q) return;
    int cb = bid - 2176;
    int b = cb >> 3, chunk = cb & 7;
    int l0 = chunk*50;
    for (int i=tid; i<NFILT*2*KW; i+=256) sm.c.cwsh[i] = conv_w[i];
    if (tid == 0 && do_d){
      float m0=emaxP[b*4+0], m1=emaxP[b*4+1], m2=emaxP[b*4+2], m3=emaxP[b*4+3];
      float gm = fmaxf(fmaxf(m0,m1), fmaxf(m2,m3));
      float gs = esumP[b*4+0]*__expf(m0-gm) + esumP[b*4+1]*__expf(m1-gm)
               + esumP[b*4+2]*__expf(m2-gm) + esumP[b*4+3]*__expf(m3-gm);
      sm.c.stat2[0] = gm; sm.c.stat2[1] = 1.0f/gs;
    }
    __syncthreads();
    float gm = sm.c.stat2[0], ginv = sm.c.stat2[1];
    for (int i=tid; i<80; i+=256){
      int pos = l0 - PADW + i;
      float w = 0.f, as = 0.f;
      if (do_d && pos >= 0 && pos < Lsz){
        w = __expf(ebufP[b*Lsz + pos] - gm) * ginv;
        as = awsP[b*Lsz + pos] + w;
      }
      sm.c.hists[0][i] = w;
      sm.c.hists[1][i] = as;
    }
    __syncthreads();
    for (int task=tid; task<NFILT*50; task+=256){
      int f = task & 31, ll = task >> 5;
      float a = 0.0f;
      const float* c0 = &sm.c.cwsh[(f*2+0)*KW];
      const float* c1 = &sm.c.cwsh[(f*2+1)*KW];
      #pragma unroll
      for (int k=0;k<KW;k++) a += sm.c.hists[0][ll+k]*c0[k] + sm.c.hists[1][ll+k]*c1[k];
      sm.c.convo[f][ll] = a;
    }
    __syncthreads();
    for (int task=tid; task<50*ATTNsz; task+=256){
      int a = task & 127, ll = task >> 7;
      float s = 0.0f;
      const float* wl = wloc + a*NFILT;
      #pragma unroll
      for (int f=0;f<NFILT;f++) s += sm.c.convo[f][ll]*wl[f];
      loc[((size_t)b*Lsz + l0 + ll)*ATTNsz + a] = s;
    }
  } else {
    // ---- updater: finalize aw(t-1) -> out_align, aws ping-pong
    if (!do_d) return;
    int b = bid - 2304;
    __shared__ float st2[2];
    if (tid == 0){
      float m0=emaxP[b*4+0], m1=emaxP[b*4+1], m2=emaxP[b*4+2], m3=emaxP[b*4+3];
      float gm = fmaxf(fmaxf(m0,m1), fmaxf(m2,m3));
      float gs = esumP[b*4+0]*__expf(m0-gm) + esumP[b*4+1]*__expf(m1-gm)
               + esumP[b*4+2]*__expf(m2-gm) + esumP[b*4+3]*__expf(m3-gm);
      st2[0] = gm; st2[1] = 1.0f/gs;
    }
    __syncthreads();
    float gm = st2[0], ginv = st2[1];
    for (int l=tid; l<Lsz; l+=256){
      float w = __expf(ebufP[b*Lsz + l] - gm) * ginv;
      awsQ[b*Lsz + l] = awsP[b*Lsz + l] + w;
      out_align[((size_t)b*Tsz + (t-1))*Lsz + l] = w;
    }
  }
}

// ---------------- P2: q-cell+pq+energies+cpart ; d-cell+mel ----------------
// blocks: [0,64) = (b, lc): q path ; [64,96) = (b, half): d path
__global__ void __launch_bounds__(256) kmidB(
    int t, int do_q, int do_d,
    cfp qpart, cfp dpart,
    cfp qcP, fp qcQ, fp qh_state,
    cfp dcP, fp dcQ, fp dh_state,
    chp h_wq, cfp vvec, cfp loc, cfp pm, cfp memory,
    cfp cpartP, cfp emaxP, cfp esumP,
    fp cpartQ, fp emaxQ, fp esumQ, fp ebufQ,
    cfp q_bih, cfp q_bhh, cfp d_bih, cfp d_bhh,
    chp h_proj, cfp proj_b, chp h_gate, cfp gate_b,
    fp out_mel, fp out_stop)
{
  int bid = blockIdx.x, tid = threadIdx.x;
  __shared__ __align__(16) float zsh[4096];
  if (bid < 64){
    if (!do_q) return;
    int b = bid & 15, lc = bid >> 4;
    int l0 = lc*100;
    __shared__ __align__(16) h2 qh2l[512];
    __shared__ float pqv[128], vsh[128];
    __shared__ float esh[100], pesh[100];
    __shared__ float red[256];
    __shared__ __align__(16) float4 psum[128];
    // 1. reduce q partials + bias
    #pragma unroll
    for (int i=0;i<4;i++){
      int r4 = (tid + i*256)*4;
      float4 bi = ldf4(q_bih + r4), bh = ldf4(q_bhh + r4);
      float4 a = {bi.x+bh.x, bi.y+bh.y, bi.z+bh.z, bi.w+bh.w};
      #pragma unroll
      for (int c=0;c<7;c++){
        float4 p = ldf4(qpart + ((size_t)(c*16 + b))*4096 + r4);
        a.x += p.x; a.y += p.y; a.z += p.z; a.w += p.w;
      }
      *reinterpret_cast<float4*>(&zsh[r4]) = a;
    }
    __syncthreads();
    // 2. cell
    {
      int j4 = tid*4;
      float4 zi = ldf4(&zsh[j4]), zf = ldf4(&zsh[1024+j4]);
      float4 zg = ldf4(&zsh[2048+j4]), zo = ldf4(&zsh[3072+j4]);
      float4 cp = ldf4(qcP + b*QHsz + j4);
      float4 cn, hn;
      cn.x = sigm(zf.x)*cp.x + sigm(zi.x)*tanhfast(zg.x); hn.x = sigm(zo.x)*tanhfast(cn.x);
      cn.y = sigm(zf.y)*cp.y + sigm(zi.y)*tanhfast(zg.y); hn.y = sigm(zo.y)*tanhfast(cn.y);
      cn.z = sigm(zf.z)*cp.z + sigm(zi.z)*tanhfast(zg.z); hn.z = sigm(zo.z)*tanhfast(cn.z);
      cn.w = sigm(zf.w)*cp.w + sigm(zi.w)*tanhfast(zg.w); hn.w = sigm(zo.w)*tanhfast(cn.w);
      if (lc == 0){
        *reinterpret_cast<float4*>(qcQ + b*QHsz + j4) = cn;
        *reinterpret_cast<float4*>(qh_state + b*QHsz + j4) = hn;
      }
      qh2l[tid*2+0] = pk2(hn.x, hn.y);
      qh2l[tid*2+1] = pk2(hn.z, hn.w);
    }
    if (tid < 128) vsh[tid] = vvec[tid];
    __syncthreads();
    // 3. pq = wq . qh  (fp16 weights, 2 threads per row)
    {
      int r = tid >> 1, kh = tid & 1;
      const h2* wr = (const h2*)(h_wq + (size_t)r*QHsz + kh*512);
      const h2* xr = &qh2l[kh*256];
      float acc = 0.f;
      #pragma unroll 4
      for (int k=0;k<256;k+=8){
        F4H wA, wB, xA, xB;
        wA.f = ldf4((const float*)(wr + k));
        wB.f = ldf4((const float*)(wr + k + 4));
        xA.f = ldf4((const float*)(xr + k));
        xB.f = ldf4((const float*)(xr + k + 4));
        #pragma unroll
        for (int j=0;j<4;j++){
          acc = fdot2f(wA.h[j], xA.h[j], acc);
          acc = fdot2f(wB.h[j], xB.h[j], acc);
        }
      }
      acc += __shfl_xor(acc, 1, 64);
      if (kh == 0) pqv[r] = acc;
    }
    __syncthreads();
    // 4. energies for 100 l's
    {
      int ll = tid >> 1, ah = tid & 1;
      float e = 0.f;
      if (ll < 100){
        int l = l0 + ll;
        const float* lp = loc + ((size_t)b*Lsz + l)*ATTNsz + ah*64;
        const float* pp = pm  + ((size_t)b*Lsz + l)*ATTNsz + ah*64;
        const float* pqa = &pqv[ah*64];
        const float* va  = &vsh[ah*64];
        #pragma unroll 4
        for (int a=0;a<64;a+=4){
          float4 l4 = ldf4(lp+a), p4 = ldf4(pp+a);
          e += tanhfast(pqa[a+0]+l4.x+p4.x)*va[a+0];
          e += tanhfast(pqa[a+1]+l4.y+p4.y)*va[a+1];
          e += tanhfast(pqa[a+2]+l4.z+p4.z)*va[a+2];
          e += tanhfast(pqa[a+3]+l4.w+p4.w)*va[a+3];
        }
      }
      e += __shfl_xor(e, 1, 64);
      if (ll < 100 && ah == 0) esh[ll] = e;
    }
    __syncthreads();
    // 5. local softmax stats
    float lm = -1e30f;
    for (int i=tid; i<100; i+=256) lm = fmaxf(lm, esh[i]);
    red[tid] = lm; __syncthreads();
    for (int s=128; s>0; s>>=1){ if (tid<s) red[tid] = fmaxf(red[tid], red[tid+s]); __syncthreads(); }
    float mx = red[0]; __syncthreads();
    float ls = 0.f;
    for (int i=tid; i<100; i+=256){ float p = __expf(esh[i]-mx); pesh[i] = p; ls += p; }
    red[tid] = ls; __syncthreads();
    for (int s=128; s>0; s>>=1){ if (tid<s) red[tid] += red[tid+s]; __syncthreads(); }
    for (int i=tid; i<100; i+=256) ebufQ[b*Lsz + l0 + i] = esh[i];
    if (tid == 0){ emaxQ[b*4+lc] = mx; esumQ[b*4+lc] = red[0]; }
    __syncthreads();
    // 6. cpart[e] = sum_l pesh[l] * mem[l][e]
    {
      int e4 = tid & 127, lh = tid >> 7;
      const float* mp = memory + ((size_t)b*Lsz + l0)*ENC + e4*4;
      float4 a = {0.f,0.f,0.f,0.f};
      for (int l = lh*50; l < lh*50+50; l++){
        float w = pesh[l];
        float4 m4 = ldf4(mp + (size_t)l*ENC);
        a.x += w*m4.x; a.y += w*m4.y; a.z += w*m4.z; a.w += w*m4.w;
      }
      if (lh == 1) psum[e4] = a;
      __syncthreads();
      if (lh == 0){
        float4 p = psum[e4];
        a.x += p.x; a.y += p.y; a.z += p.z; a.w += p.w;
        *reinterpret_cast<float4*>(cpartQ + ((size_t)b*4 + lc)*512 + e4*4) = a;
      }
    }
  } else {
    if (!do_d) return;
    int db = bid - 64;
    int b = db & 15, half = db >> 4;
    int tm = t - 1;
    int lane = tid & 63, wv = tid >> 6;
    __shared__ __align__(16) h2 feath[768];
    __shared__ float scs[4];
    // 1. reduce d partials + bias
    #pragma unroll
    for (int i=0;i<4;i++){
      int r4 = (tid + i*256)*4;
      float4 bi = ldf4(d_bih + r4), bh = ldf4(d_bhh + r4);
      float4 a = {bi.x+bh.x, bi.y+bh.y, bi.z+bh.z, bi.w+bh.w};
      #pragma unroll
      for (int c=0;c<10;c++){
        float4 p = ldf4(dpart + ((size_t)(c*16 + b))*4096 + r4);
        a.x += p.x; a.y += p.y; a.z += p.z; a.w += p.w;
      }
      *reinterpret_cast<float4*>(&zsh[r4]) = a;
    }
    if (tid == 0){
      float m0=emaxP[b*4+0], m1=emaxP[b*4+1], m2=emaxP[b*4+2], m3=emaxP[b*4+3];
      float gm = fmaxf(fmaxf(m0,m1), fmaxf(m2,m3));
      float e0=__expf(m0-gm), e1=__expf(m1-gm), e2=__expf(m2-gm), e3=__expf(m3-gm);
      float gs = esumP[b*4+0]*e0 + esumP[b*4+1]*e1 + esumP[b*4+2]*e2 + esumP[b*4+3]*e3;
      float inv = 1.0f/gs;
      scs[0]=e0*inv; scs[1]=e1*inv; scs[2]=e2*inv; scs[3]=e3*inv;
    }
    __syncthreads();
    // 2. cell
    {
      int j4 = tid*4;
      float4 zi = ldf4(&zsh[j4]), zf = ldf4(&zsh[1024+j4]);
      float4 zg = ldf4(&zsh[2048+j4]), zo = ldf4(&zsh[3072+j4]);
      float4 cp = ldf4(dcP + b*DHsz + j4);
      float4 cn, hn;
      cn.x = sigm(zf.x)*cp.x + sigm(zi.x)*tanhfast(zg.x); hn.x = sigm(zo.x)*tanhfast(cn.x);
      cn.y = sigm(zf.y)*cp.y + sigm(zi.y)*tanhfast(zg.y); hn.y = sigm(zo.y)*tanhfast(cn.y);
      cn.z = sigm(zf.z)*cp.z + sigm(zi.z)*tanhfast(zg.z); hn.z = sigm(zo.z)*tanhfast(cn.z);
      cn.w = sigm(zf.w)*cp.w + sigm(zi.w)*tanhfast(zg.w); hn.w = sigm(zo.w)*tanhfast(cn.w);
      if (half == 0){
        *reinterpret_cast<float4*>(dcQ + b*DHsz + j4) = cn;
        *reinterpret_cast<float4*>(dh_state + b*DHsz + j4) = hn;
      }
      feath[tid*2+0] = pk2(hn.x, hn.y);
      feath[tid*2+1] = pk2(hn.z, hn.w);
    }
    __syncthreads();
    // 3. ctx(t-1) finalize into feath[512..768)
    {
      float s0=scs[0], s1=scs[1], s2=scs[2], s3=scs[3];
      int i0 = tid*2;
      const float* cp = cpartP + (size_t)b*2048;
      float v0 = s0*cp[i0]   + s1*cp[512+i0]   + s2*cp[1024+i0]   + s3*cp[1536+i0];
      float v1 = s0*cp[i0+1] + s1*cp[512+i0+1] + s2*cp[1024+i0+1] + s3*cp[1536+i0+1];
      feath[512 + tid] = pk2(v0, v1);
    }
    __syncthreads();
    // 4. mel / stop (fp16 weights)
    int rbeg = half*40, rend = half ? 81 : 40;
    for (int r = rbeg + wv; r < rend; r += 4){
      const h2* wr = (r < 80) ? (const h2*)(h_proj + (size_t)r*1536) : (const h2*)h_gate;
      float acc = 0.0f;
      #pragma unroll
      for (int m=0;m<3;m++){
        int k4 = (lane + 64*m)*4;   // h2 index
        F4H w, x;
        w.f = ldf4((const float*)(wr + k4));
        x.f = ldf4((const float*)(&feath[k4]));
        #pragma unroll
        for (int j=0;j<4;j++) acc = fdot2f(w.h[j], x.h[j], acc);
      }
      #pragma unroll
      for (int off=32; off>0; off>>=1) acc += __shfl_xor(acc, off, 64);
      if (lane == 0){
        if (r < 80) out_mel[((size_t)b*Tsz + tm)*NMELS + r] = acc + proj_b[r];
        else        out_stop[b*Tsz + tm] = sigm(acc + gate_b[0]);
      }
    }
  }
}

extern "C" void kernel_launch(void* const* d_in, const int* in_sizes, int n_in,
                              void* d_out, int out_size, void* d_ws, size_t ws_size,
                              hipStream_t stream)
{
  const float* memory  = (const float*)d_in[0];
  const float* teacher = (const float*)d_in[2];
  const float* pre_w1  = (const float*)d_in[3];
  const float* pre_w2  = (const float*)d_in[4];
  const float* q_wih   = (const float*)d_in[5];
  const float* q_whh   = (const float*)d_in[6];
  const float* q_bih   = (const float*)d_in[7];
  const float* q_bhh   = (const float*)d_in[8];
  const float* d_wih   = (const float*)d_in[9];
  const float* d_whh   = (const float*)d_in[10];
  const float* d_bih   = (const float*)d_in[11];
  const float* d_bhh   = (const float*)d_in[12];
  const float* attn_wq   = (const float*)d_in[13];
  const float* attn_wm   = (const float*)d_in[14];
  const float* attn_conv = (const float*)d_in[15];
  const float* attn_wloc = (const float*)d_in[16];
  const float* attn_v    = (const float*)d_in[17];
  const float* proj_w  = (const float*)d_in[18];
  const float* proj_b  = (const float*)d_in[19];
  const float* gate_w  = (const float*)d_in[20];
  const float* gate_b  = (const float*)d_in[21];

  float* ws = (float*)d_ws;
  float* dec_ins  = ws;                 // 819200
  float* pm       = dec_ins + 819200;   // 819200
  float* loc      = pm + 819200;        // 819200
  float* qpart    = loc + 819200;       // 458752
  float* dpart    = qpart + 458752;     // 655360
  float* ebuf2    = dpart + 655360;     // 2*6400
  float* emax2    = ebuf2 + 12800;      // 2*64
  float* esum2    = emax2 + 128;        // 2*64
  float* cpart2   = esum2 + 128;        // 2*32768
  float* qh_state = cpart2 + 65536;     // 16384
  float* dh_state = qh_state + 16384;   // 16384
  float* qc2      = dh_state + 16384;   // 2*16384
  float* dc2      = qc2 + 32768;        // 2*16384
  float* aws2     = dc2 + 32768;        // 2*6400
  float* fend     = aws2 + 12800;

  hf* h_qwih = (hf*)fend;               // 4096*768
  hf* h_qwhh = h_qwih + 3145728;        // 4096*1024
  hf* h_dwih = h_qwhh + 4194304;        // 4096*1536
  hf* h_dwhh = h_dwih + 6291456;        // 4096*1024
  hf* h_wq   = h_dwhh + 4194304;        // 128*1024
  hf* h_proj = h_wq + 131072;           // 80*1536
  hf* h_gate = h_proj + 122880;         // 1536

  float* out_mel   = (float*)d_out;
  float* out_align = out_mel + (size_t)Bsz*Tsz*NMELS;
  float* out_stop  = out_align + (size_t)Bsz*Tsz*Lsz;

  const int stateN = 16384+16384+32768+32768+12800;
  kzero<<<dim3((stateN+255)/256), dim3(256), 0, stream>>>(qh_state, stateN);
  kcvt<<<dim3(3145728/1024), dim3(256), 0, stream>>>(q_wih, h_qwih, 3145728);
  kcvt<<<dim3(4194304/1024), dim3(256), 0, stream>>>(q_whh, h_qwhh, 4194304);
  kcvt<<<dim3(6291456/1024), dim3(256), 0, stream>>>(d_wih, h_dwih, 6291456);
  kcvt<<<dim3(4194304/1024), dim3(256), 0, stream>>>(d_whh, h_dwhh, 4194304);
  kcvt<<<dim3(131072/1024), dim3(256), 0, stream>>>(attn_wq, h_wq, 131072);
  kcvt<<<dim3(122880/1024), dim3(256), 0, stream>>>(proj_w, h_proj, 122880);
  kcvt<<<dim3(2), dim3(256), 0, stream>>>(gate_w, h_gate, 1536);
  kprenet2<<<dim3(16*13), dim3(256), 0, stream>>>(teacher, pre_w1, pre_w2, dec_ins);
  kpm2<<<dim3(400), dim3(256), 0, stream>>>(memory, attn_wm, pm);

  for (int t = 0; t <= Tsz; t++){
    int pp = (t+1)&1, qq = t&1;
    int do_q = (t < Tsz) ? 1 : 0;
    int do_d = (t > 0) ? 1 : 0;
    kgatesA<<<dim3(2320), dim3(256), 0, stream>>>(
      t, do_q, do_d,
      dec_ins, qh_state, dh_state,
      cpart2 + pp*32768, emax2 + pp*64, esum2 + pp*64, ebuf2 + pp*6400,
      aws2 + pp*6400, aws2 + qq*6400,
      qpart, dpart, loc, out_align,
      h_qwih, h_qwhh, h_dwih, h_dwhh,
      attn_conv, attn_wloc);
    kmidB<<<dim3(96), dim3(256), 0, stream>>>(
      t, do_q, do_d,
      qpart, dpart,
      qc2 + pp*16384, qc2 + qq*16384, qh_state,
      dc2 + pp*16384, dc2 + qq*16384, dh_state,
      h_wq, attn_v, loc, pm, memory,
      cpart2 + pp*32768, emax2 + pp*64, esum2 + pp*64,
      cpart2 + qq*32768, emax2 + qq*64, esum2 + qq*64, ebuf2 + qq*6400,
      q_bih, q_bhh, d_bih, d_bhh,
      h_proj, proj_b, h_gate, gate_b,
      out_mel, out_stop);
  }
}